// Round 11
// baseline (644.810 us; speedup 1.0000x reference)
//
#include <hip/hip_runtime.h>
#include <math.h>

#ifndef M_PI
#define M_PI 3.14159265358979323846
#endif

#define BB 1024
#define SIZE 512
#define NF 128
#define WIDTH 32
#define TOTAL (SIZE*NF)

// DPP-based unsigned max reduce step (VALU latency, no LDS pipe)
#define DPP_UMAX(x, ctrl, rmask) { \
    unsigned _t = (unsigned)__builtin_amdgcn_update_dpp(0, (int)(x), (ctrl), (rmask), 0xf, false); \
    if (_t > (x)) (x) = _t; }

__device__ __forceinline__ float readlanef(float x, int l) {
    return __int_as_float(__builtin_amdgcn_readlane(__float_as_int(x), l));
}

// ---------------------------------------------------------------------------
// Kernel 1: per-sample FNO frontend -> pooled[b][32], pos[r][b] (gather map)
// ---------------------------------------------------------------------------
__global__ __launch_bounds__(256) void fno_pooled_kernel(
    const int*   __restrict__ n,
    const float* __restrict__ lift_W,
    const float* __restrict__ lift_b,
    const float* __restrict__ spec_Wr,
    const float* __restrict__ spec_Wi,
    const float* __restrict__ pw_W,
    const float* __restrict__ pw_b,
    float* __restrict__ pooled_g,
    signed char* __restrict__ pos_g)
{
    __shared__ float nf[SIZE];
    __shared__ float c32[32], s32[32];
    __shared__ float Gre[16], Gim[16];
    __shared__ float wsum[4][32];
    __shared__ float Arr[WIDTH][16], Aii[WIDTH][16];
    __shared__ float lowr[WIDTH][16], lowi[WIDTH][16];
    __shared__ float pwl[WIDTH], cb0[WIDTH];
    __shared__ float Brr[WIDTH], Bii[WIDTH];

    const int b = blockIdx.x;
    const int t = threadIdx.x;
    const int lane = t & 63;
    const int wave = t >> 6;

    if (t < 32) {
        float ang = (float)t * (2.0f * (float)M_PI / 32.0f);
        c32[t] = cosf(ang);
        s32[t] = sinf(ang);
    }
    for (int p = t; p < SIZE; p += 256) nf[p] = (float)n[b*SIZE + p];
    __syncthreads();

    // gather map via ballot scan (wave 0): pos[r][b]
    if (wave == 0) {
        int base = 0;
        for (int c = 0; c < 8; ++c) {
            int p = c*64 + lane;
            bool occ = (nf[p] != 0.0f);
            unsigned long long mask = __ballot(occ);
            int prefix = __popcll(mask & ((1ull << lane) - 1ull));
            int pos = base + prefix;
            pos_g[(size_t)p*BB + b] = (occ && pos < NF) ? (signed char)pos : (signed char)-1;
            base += __popcll(mask);
        }
    }

    float gre[16], gim[16];
    #pragma unroll
    for (int m = 0; m < 16; ++m) { gre[m] = 0.f; gim[m] = 0.f; }
    for (int p = t; p < SIZE; p += 256) {
        float v = nf[p];
        int x = p >> 4, y = p & 15;
        #pragma unroll
        for (int kx = 0; kx < 4; ++kx) {
            #pragma unroll
            for (int ky = 0; ky < 4; ++ky) {
                int idx = (kx*x + 2*ky*y) & 31;
                gre[kx*4+ky] += v * c32[idx];
                gim[kx*4+ky] -= v * s32[idx];
            }
        }
    }
    #pragma unroll
    for (int m = 0; m < 16; ++m) {
        for (int off = 32; off > 0; off >>= 1) {
            gre[m] += __shfl_xor(gre[m], off, 64);
            gim[m] += __shfl_xor(gim[m], off, 64);
        }
    }
    if (lane == 0) {
        #pragma unroll
        for (int m = 0; m < 16; ++m) { wsum[wave][m] = gre[m]; wsum[wave][16+m] = gim[m]; }
    }
    __syncthreads();
    if (t < 32) {
        float s = wsum[0][t] + wsum[1][t] + wsum[2][t] + wsum[3][t];
        if (t < 16) Gre[t] = s; else Gim[t-16] = s;
    }

    for (int idx = t; idx < 512; idx += 256) {
        int o = idx >> 4, m = idx & 15;
        float ar = 0.f, ai = 0.f;
        for (int ii = 0; ii < WIDTH; ++ii) {
            float lw = lift_W[ii];
            ar += lw * spec_Wr[ii*512 + o*16 + m];
            ai += lw * spec_Wi[ii*512 + o*16 + m];
        }
        Arr[o][m] = ar; Aii[o][m] = ai;
    }
    if (t < 32) {
        float br = 0.f, bi = 0.f, pl = 0.f, cb = 0.f;
        for (int ii = 0; ii < WIDTH; ++ii) {
            float lb = lift_b[ii];
            br += lb * spec_Wr[ii*512 + t*16 + 0];
            bi += lb * spec_Wi[ii*512 + t*16 + 0];
            pl += lift_W[ii] * pw_W[ii*WIDTH + t];
            cb += lb * pw_W[ii*WIDTH + t];
        }
        Brr[t] = br; Bii[t] = bi;
        pwl[t] = pl;
        cb0[t] = cb + pw_b[t];
    }
    __syncthreads();

    for (int idx = t; idx < 512; idx += 256) {
        int o = idx >> 4, m = idx & 15;
        float gr = Gre[m], gi = Gim[m];
        float ar = Arr[o][m], ai = Aii[o][m];
        float lr = gr*ar - gi*ai;
        float li = gr*ai + gi*ar;
        if (m == 0) { lr += 512.f * Brr[o]; li += 512.f * Bii[o]; }
        lowr[o][m] = lr; lowi[o][m] = li;
    }
    __syncthreads();

    const int o  = t >> 3;
    const int xg = t & 7;
    const float plo = pwl[o], cbo = cb0[o];
    float acc = 0.f;
    const float inv32 = 1.0f/32.0f, inv16 = 1.0f/16.0f;
    for (int xi = 0; xi < 4; ++xi) {
        int x = xg*4 + xi;
        float Tre[4], Tim[4];
        #pragma unroll
        for (int ky = 0; ky < 4; ++ky) { Tre[ky] = 0.f; Tim[ky] = 0.f; }
        #pragma unroll
        for (int kx = 0; kx < 4; ++kx) {
            int idx = (kx*x) & 31;
            float c = c32[idx], s = s32[idx];
            #pragma unroll
            for (int ky = 0; ky < 4; ++ky) {
                float lr = lowr[o][kx*4+ky], li = lowi[o][kx*4+ky];
                Tre[ky] += lr*c - li*s;
                Tim[ky] += lr*s + li*c;
            }
        }
        #pragma unroll
        for (int ky = 0; ky < 4; ++ky) { Tre[ky] *= inv32; Tim[ky] *= inv32; }
        for (int y = 0; y < 16; ++y) {
            float hsv = Tre[0];
            #pragma unroll
            for (int ky = 1; ky < 4; ++ky) {
                int idx = (2*ky*y) & 31;
                hsv += 2.f*(Tre[ky]*c32[idx] - Tim[ky]*s32[idx]);
            }
            hsv *= inv16;
            float z = hsv + nf[x*16 + y]*plo + cbo;
            acc += tanhf(z);
        }
    }
    acc += __shfl_down(acc, 4, 8);
    acc += __shfl_down(acc, 2, 8);
    acc += __shfl_down(acc, 1, 8);
    if ((t & 7) == 0) pooled_g[b*WIDTH + o] = acc * (1.0f/512.0f);
}

// ---------------------------------------------------------------------------
// Kernel 2: r-major gathered build (proj_W row segment in registers, reused
// across 256 samples). Writes A_ws coalesced.
// ---------------------------------------------------------------------------
__global__ __launch_bounds__(128) void build_kernel(
    const float* __restrict__ M_base,
    const float* __restrict__ proj_W,
    const float* __restrict__ proj_b,
    const float* __restrict__ pooled_g,
    const signed char* __restrict__ pos_g,
    float* __restrict__ A_ws)
{
    __shared__ float pooled_l[256*WIDTH];   // 32 KB
    __shared__ signed char posl[256];

    const int r  = blockIdx.x >> 2;
    const int b0 = (blockIdx.x & 3) * 256;
    const int j  = threadIdx.x;

    {
        const float4* src = (const float4*)(pooled_g + (size_t)b0*WIDTH);
        float4* dst = (float4*)pooled_l;
        for (int idx = j; idx < 256*WIDTH/4; idx += 128) dst[idx] = src[idx];
        if (j < 64) ((int*)posl)[j] = ((const int*)(pos_g + (size_t)r*BB + b0))[j];
    }

    float wj[WIDTH];
    #pragma unroll
    for (int o = 0; o < WIDTH; ++o) wj[o] = proj_W[(size_t)o*TOTAL + r*NF + j];
    const float base = M_base[r*NF + j] + proj_b[r*NF + j];
    __syncthreads();

    for (int bb = 0; bb < 256; ++bb) {
        int pos = posl[bb];
        if (pos < 0) continue;
        const float* pl = &pooled_l[bb*WIDTH];
        float acc = base;
        #pragma unroll
        for (int o = 0; o < WIDTH; ++o) acc += pl[o]*wj[o];
        A_ws[((size_t)(b0+bb)*NF + pos)*NF + j] = acc;
    }
}

// ---------------------------------------------------------------------------
// Kernel 3: rank-4 blocked LU with LOOKAHEAD. 576 threads:
// wave 0 = pivot-only; waves 1-8: row i = u&127, quarter q, 8 float4 of A.
// Per iter p: {pivot(p) || wide-update(p-1, groups G>p)} -> Raw(p) publish ->
// narrow-update(group p+1) + pcol(p+1) publish. Mb/coefb/pr4 double-buffered.
// Pivot search: row index encoded in low 7 bits of the abs key -> one DPP
// chain + one readlane (no ballot/ffs).
// Output planar: out[b] = logabs, out[BB+b] = 0 or pi.
// ---------------------------------------------------------------------------
__global__ __launch_bounds__(576) void lu_kernel(
    const float* __restrict__ A_ws,
    float* __restrict__ out)
{
    __shared__ __align__(16) float pcol[128*4];
    __shared__ __align__(16) float Raw[4*128];
    __shared__ __align__(16) float coefb[2][128*4];
    __shared__ float Mb[2][16];
    __shared__ int   pr4[2][4];
    __shared__ float pvbuf[128];
    __shared__ int   pivseq[128];

    const int b = blockIdx.x;
    const int t = threadIdx.x;
    const int lane = t & 63;
    const int u = t - 64;
    const int i = u & 127;
    const int q = (u >> 7) & 3;

    float4 Areg[8];
    if (t >= 64) {
        const float4* src = (const float4*)(A_ws + (size_t)b*(NF*NF) + i*NF + q*32);
        #pragma unroll
        for (int g = 0; g < 8; ++g) Areg[g] = src[g];
        if (q == 0) *((float4*)&pcol[i*4]) = Areg[0];
    }

    bool done_i = false;      // matrix: row retired (after its wide replace)
    int  fp_prev = -1;        // matrix: pivot-slot discovered last iter
    bool done0 = false, done1 = false;  // pivot wave state
    __syncthreads();

    for (int p = 0; p < 32; ++p) {
        const int cb = p & 1;

        // ---------- phase 1: pivot(p) [wave0]  ||  wide-update(p-1) [matrix] ----------
        if (t < 64) {
            float4 r0 = *((const float4*)&pcol[lane*4]);
            float4 r1 = *((const float4*)&pcol[lane*4 + 256]);
            float v0[4] = { r0.x, r0.y, r0.z, r0.w };
            float v1[4] = { r1.x, r1.y, r1.z, r1.w };
            float lr0[4], lr1[4];
            int   prreg[4];

            #pragma unroll
            for (int k = 0; k < 4; ++k) {
                unsigned a0 = __float_as_uint(v0[k]) & 0x7fffffffu;
                unsigned a1 = __float_as_uint(v1[k]) & 0x7fffffffu;
                unsigned key0 = done0 ? 0u : ((a0 & 0xffffff80u) | (unsigned)lane);
                unsigned key1 = done1 ? 0u : ((a1 & 0xffffff80u) | (unsigned)(lane + 64));
                unsigned key = (key1 > key0) ? key1 : key0;
                DPP_UMAX(key, 0x111, 0xf);   // row_shr:1
                DPP_UMAX(key, 0x112, 0xf);   // row_shr:2
                DPP_UMAX(key, 0x114, 0xf);   // row_shr:4
                DPP_UMAX(key, 0x118, 0xf);   // row_shr:8
                DPP_UMAX(key, 0x142, 0xa);   // row_bcast:15
                DPP_UMAX(key, 0x143, 0xc);   // row_bcast:31
                const unsigned best = (unsigned)__builtin_amdgcn_readlane((int)key, 63);
                const int row = (int)(best & 127u);
                const int lw  = row & 63;
                const bool lowh = (row < 64);
                const float pv = lowh ? readlanef(v0[k], lw) : readlanef(v1[k], lw);
                prreg[k] = row;
                const float inv = 1.0f / pv;
                float l0 = (done0 || row == lane)      ? 0.f : v0[k] * inv;
                float l1 = (done1 || row == lane + 64) ? 0.f : v1[k] * inv;
                lr0[k] = l0; lr1[k] = l1;
                if (row == lane)      done0 = true;
                if (row == lane + 64) done1 = true;
                #pragma unroll
                for (int j = 0; j < 4; ++j) if (j > k) {
                    float ukj = lowh ? readlanef(v0[j], lw) : readlanef(v1[j], lw);
                    v0[j] -= l0 * ukj;
                    v1[j] -= l1 * ukj;
                }
                if (lane == 0) { pivseq[4*p+k] = row; pvbuf[4*p+k] = pv; }
            }

            // L11 strict-lower entries via readlane (uniform)
            const int pa = prreg[1], pb_ = prreg[2], pc = prreg[3];
            const float Lt10 = (pa  < 64) ? readlanef(lr0[0], pa)  : readlanef(lr1[0], pa - 64);
            const float Lt20 = (pb_ < 64) ? readlanef(lr0[0], pb_) : readlanef(lr1[0], pb_ - 64);
            const float Lt21 = (pb_ < 64) ? readlanef(lr0[1], pb_) : readlanef(lr1[1], pb_ - 64);
            const float Lt30 = (pc  < 64) ? readlanef(lr0[0], pc)  : readlanef(lr1[0], pc - 64);
            const float Lt31 = (pc  < 64) ? readlanef(lr0[1], pc)  : readlanef(lr1[1], pc - 64);
            const float Lt32 = (pc  < 64) ? readlanef(lr0[2], pc)  : readlanef(lr1[2], pc - 64);

            // M = (I+Lt)^{-1} closed form (unit lower)
            const float m10 = -Lt10;
            const float m21 = -Lt21;
            const float m32 = -Lt32;
            const float m20 = -Lt20 + Lt21*Lt10;
            const float m31 = -Lt31 + Lt32*Lt21;
            const float m30 = -Lt30 + Lt31*Lt10 + Lt32*Lt20 - Lt32*Lt21*Lt10;

            if (lane == 0) {
                pr4[cb][0] = prreg[0]; pr4[cb][1] = prreg[1];
                pr4[cb][2] = prreg[2]; pr4[cb][3] = prreg[3];
                float* M = Mb[cb];
                M[0]=1.f;  M[1]=0.f;  M[2]=0.f;  M[3]=0.f;
                M[4]=m10;  M[5]=1.f;  M[6]=0.f;  M[7]=0.f;
                M[8]=m20;  M[9]=m21;  M[10]=1.f; M[11]=0.f;
                M[12]=m30; M[13]=m31; M[14]=m32; M[15]=1.f;
            }
            // composite coefs: coef = -(lrow . M)
            {
                float c0 = -(lr0[0] + lr0[1]*m10 + lr0[2]*m20 + lr0[3]*m30);
                float c1 = -(lr0[1] + lr0[2]*m21 + lr0[3]*m31);
                float c2 = -(lr0[2] + lr0[3]*m32);
                float c3 = -(lr0[3]);
                *((float4*)&coefb[cb][lane*4]) = make_float4(c0, c1, c2, c3);
                float d0 = -(lr1[0] + lr1[1]*m10 + lr1[2]*m20 + lr1[3]*m30);
                float d1 = -(lr1[1] + lr1[2]*m21 + lr1[3]*m31);
                float d2 = -(lr1[2] + lr1[3]*m32);
                float d3 = -(lr1[3]);
                *((float4*)&coefb[cb][(lane+64)*4]) = make_float4(d0, d1, d2, d3);
            }
        } else if (p > 0) {
            // wide-update(p-1): groups G > p, buffers [cb^1], Raw = Raw(p-1)
            if (fp_prev >= 0) {
                const float* M = &Mb[cb^1][fp_prev*4];
                const float m0 = M[0], m1 = M[1], m2 = M[2], m3 = M[3];
                #pragma unroll
                for (int g = 0; g < 8; ++g) {
                    const int G = q*8 + g;
                    if (G > p) {
                        const int cbase = G*4;
                        float4 r0v = *((const float4*)&Raw[0*128 + cbase]);
                        float4 r1v = *((const float4*)&Raw[1*128 + cbase]);
                        float4 r2v = *((const float4*)&Raw[2*128 + cbase]);
                        float4 r3v = *((const float4*)&Raw[3*128 + cbase]);
                        Areg[g].x = m0*r0v.x + m1*r1v.x + m2*r2v.x + m3*r3v.x;
                        Areg[g].y = m0*r0v.y + m1*r1v.y + m2*r2v.y + m3*r3v.y;
                        Areg[g].z = m0*r0v.z + m1*r1v.z + m2*r2v.z + m3*r3v.z;
                        Areg[g].w = m0*r0v.w + m1*r1v.w + m2*r2v.w + m3*r3v.w;
                    }
                }
                done_i = true;
                fp_prev = -1;
            } else if (!done_i) {
                const float4 cf = *((const float4*)&coefb[cb^1][i*4]);
                #pragma unroll
                for (int g = 0; g < 8; ++g) {
                    const int G = q*8 + g;
                    if (G > p) {
                        const int cbase = G*4;
                        float4 r0v = *((const float4*)&Raw[0*128 + cbase]);
                        float4 r1v = *((const float4*)&Raw[1*128 + cbase]);
                        float4 r2v = *((const float4*)&Raw[2*128 + cbase]);
                        float4 r3v = *((const float4*)&Raw[3*128 + cbase]);
                        Areg[g].x += cf.x*r0v.x + cf.y*r1v.x + cf.z*r2v.x + cf.w*r3v.x;
                        Areg[g].y += cf.x*r0v.y + cf.y*r1v.y + cf.z*r2v.y + cf.w*r3v.y;
                        Areg[g].z += cf.x*r0v.z + cf.y*r1v.z + cf.z*r2v.z + cf.w*r3v.z;
                        Areg[g].w += cf.x*r0v.w + cf.y*r1v.w + cf.z*r2v.w + cf.w*r3v.w;
                    }
                }
            }
        }
        __syncthreads();   // barrier A: pivot(p) results ready; wide(p-1) done

        // ---------- phase 2: pivot-row owners publish Raw(p) (pre-update) ----------
        int fp = -1;
        if (t >= 64) {
            #pragma unroll
            for (int s = 0; s < 4; ++s) if (i == pr4[cb][s]) fp = s;
            if (fp >= 0) {
                #pragma unroll
                for (int g = 0; g < 8; ++g)
                    *((float4*)&Raw[fp*128 + q*32 + g*4]) = Areg[g];
            }
        }
        __syncthreads();   // barrier B: Raw(p) ready

        // ---------- phase 3: narrow-update group p+1; publish pcol(p+1) ----------
        if (t >= 64) {
            if (p < 31) {
                const int np = p + 1;
                if (q == (np >> 3)) {
                    const int g = np & 7;
                    const int cbase = np*4;
                    float4 r0v = *((const float4*)&Raw[0*128 + cbase]);
                    float4 r1v = *((const float4*)&Raw[1*128 + cbase]);
                    float4 r2v = *((const float4*)&Raw[2*128 + cbase]);
                    float4 r3v = *((const float4*)&Raw[3*128 + cbase]);
                    float4 own = Areg[g];
                    if (fp >= 0) {
                        const float* M = &Mb[cb][fp*4];
                        own.x = M[0]*r0v.x + M[1]*r1v.x + M[2]*r2v.x + M[3]*r3v.x;
                        own.y = M[0]*r0v.y + M[1]*r1v.y + M[2]*r2v.y + M[3]*r3v.y;
                        own.z = M[0]*r0v.z + M[1]*r1v.z + M[2]*r2v.z + M[3]*r3v.z;
                        own.w = M[0]*r0v.w + M[1]*r1v.w + M[2]*r2v.w + M[3]*r3v.w;
                    } else if (!done_i) {
                        const float4 cf = *((const float4*)&coefb[cb][i*4]);
                        own.x += cf.x*r0v.x + cf.y*r1v.x + cf.z*r2v.x + cf.w*r3v.x;
                        own.y += cf.x*r0v.y + cf.y*r1v.y + cf.z*r2v.y + cf.w*r3v.y;
                        own.z += cf.x*r0v.z + cf.y*r1v.z + cf.z*r2v.z + cf.w*r3v.z;
                        own.w += cf.x*r0v.w + cf.y*r1v.w + cf.z*r2v.w + cf.w*r3v.w;
                    }
                    Areg[g] = own;
                    *((float4*)&pcol[i*4]) = own;
                }
            }
            fp_prev = fp;
        }
        __syncthreads();   // barrier C: pcol(p+1) ready, coef buffers consumable
    }

    // ---------- logabs + sign (wave 0) ----------
    if (t < 64) {
        float d0 = pvbuf[lane], d1 = pvbuf[lane + 64];
        int   ps0 = pivseq[lane], ps1 = pivseq[lane + 64];
        float ls = logf(fabsf(d0)) + logf(fabsf(d1));
        int neg = ((d0 < 0.f) ? 1 : 0) ^ ((d1 < 0.f) ? 1 : 0);
        #pragma unroll
        for (int off = 32; off > 0; off >>= 1) {
            ls  += __shfl_xor(ls,  off, 64);
            neg ^= __shfl_xor(neg, off, 64);
        }
        unsigned long long vis0 = 0ull, vis1 = 0ull;
        int trans = 0;
        for (int k = 0; k < 128; ++k) {
            bool vk = (k < 64) ? ((vis0 >> k) & 1ull) : ((vis1 >> (k - 64)) & 1ull);
            if (!vk) {
                int j = k, len = 0;
                while (true) {
                    bool vj = (j < 64) ? ((vis0 >> j) & 1ull) : ((vis1 >> (j - 64)) & 1ull);
                    if (vj) break;
                    if (j < 64) vis0 |= (1ull << j); else vis1 |= (1ull << (j - 64));
                    j = (j < 64) ? __builtin_amdgcn_readlane(ps0, j)
                                 : __builtin_amdgcn_readlane(ps1, j - 64);
                    ++len;
                }
                trans += len - 1;
            }
        }
        if (lane == 0) {
            int parity = (neg ^ (trans & 1)) & 1;
            out[b]      = ls;
            out[BB + b] = parity ? (float)M_PI : 0.0f;
        }
    }
}

// ---------------------------------------------------------------------------
extern "C" void kernel_launch(void* const* d_in, const int* in_sizes, int n_in,
                              void* d_out, int out_size, void* d_ws, size_t ws_size,
                              hipStream_t stream) {
    const int*   n       = (const int*)  d_in[0];
    const float* M_base  = (const float*)d_in[1];
    const float* lift_W  = (const float*)d_in[2];
    const float* lift_b  = (const float*)d_in[3];
    const float* spec_Wr = (const float*)d_in[4];
    const float* spec_Wi = (const float*)d_in[5];
    const float* pw_W    = (const float*)d_in[6];
    const float* pw_b    = (const float*)d_in[7];
    const float* proj_W  = (const float*)d_in[8];
    const float* proj_b  = (const float*)d_in[9];

    // ws layout: pooled 128KB | pos 512KB | (align 1MB) A_ws 64MB
    float*       pooled = (float*)d_ws;
    signed char* pos    = (signed char*)((char*)d_ws + 128*1024);
    float*       A_ws   = (float*)((char*)d_ws + (1 << 20));

    fno_pooled_kernel<<<BB, 256, 0, stream>>>(n, lift_W, lift_b, spec_Wr, spec_Wi,
                                              pw_W, pw_b, pooled, pos);
    build_kernel<<<SIZE*4, 128, 0, stream>>>(M_base, proj_W, proj_b, pooled, pos, A_ws);
    lu_kernel<<<BB, 576, 0, stream>>>(A_ws, (float*)d_out);
}

// Round 12
// 424.802 us; speedup vs baseline: 1.5179x; 1.5179x over previous
//
#include <hip/hip_runtime.h>
#include <math.h>

#ifndef M_PI
#define M_PI 3.14159265358979323846
#endif

#define BB 1024
#define SIZE 512
#define NF 128
#define WIDTH 32
#define TOTAL (SIZE*NF)

// DPP-based unsigned max reduce step (VALU latency, no LDS pipe)
#define DPP_UMAX(x, ctrl, rmask) { \
    unsigned _t = (unsigned)__builtin_amdgcn_update_dpp(0, (int)(x), (ctrl), (rmask), 0xf, false); \
    if (_t > (x)) (x) = _t; }

__device__ __forceinline__ float readlanef(float x, int l) {
    return __int_as_float(__builtin_amdgcn_readlane(__float_as_int(x), l));
}

// ---------------------------------------------------------------------------
// Kernel 1: per-sample FNO frontend -> pooled[b][32], pos[r][b] (gather map)
// ---------------------------------------------------------------------------
__global__ __launch_bounds__(256) void fno_pooled_kernel(
    const int*   __restrict__ n,
    const float* __restrict__ lift_W,
    const float* __restrict__ lift_b,
    const float* __restrict__ spec_Wr,
    const float* __restrict__ spec_Wi,
    const float* __restrict__ pw_W,
    const float* __restrict__ pw_b,
    float* __restrict__ pooled_g,
    signed char* __restrict__ pos_g)
{
    __shared__ float nf[SIZE];
    __shared__ float c32[32], s32[32];
    __shared__ float Gre[16], Gim[16];
    __shared__ float wsum[4][32];
    __shared__ float Arr[WIDTH][16], Aii[WIDTH][16];
    __shared__ float lowr[WIDTH][16], lowi[WIDTH][16];
    __shared__ float pwl[WIDTH], cb0[WIDTH];
    __shared__ float Brr[WIDTH], Bii[WIDTH];

    const int b = blockIdx.x;
    const int t = threadIdx.x;
    const int lane = t & 63;
    const int wave = t >> 6;

    if (t < 32) {
        float ang = (float)t * (2.0f * (float)M_PI / 32.0f);
        c32[t] = cosf(ang);
        s32[t] = sinf(ang);
    }
    for (int p = t; p < SIZE; p += 256) nf[p] = (float)n[b*SIZE + p];
    __syncthreads();

    // gather map via ballot scan (wave 0): pos[r][b]
    if (wave == 0) {
        int base = 0;
        for (int c = 0; c < 8; ++c) {
            int p = c*64 + lane;
            bool occ = (nf[p] != 0.0f);
            unsigned long long mask = __ballot(occ);
            int prefix = __popcll(mask & ((1ull << lane) - 1ull));
            int pos = base + prefix;
            pos_g[(size_t)p*BB + b] = (occ && pos < NF) ? (signed char)pos : (signed char)-1;
            base += __popcll(mask);
        }
    }

    float gre[16], gim[16];
    #pragma unroll
    for (int m = 0; m < 16; ++m) { gre[m] = 0.f; gim[m] = 0.f; }
    for (int p = t; p < SIZE; p += 256) {
        float v = nf[p];
        int x = p >> 4, y = p & 15;
        #pragma unroll
        for (int kx = 0; kx < 4; ++kx) {
            #pragma unroll
            for (int ky = 0; ky < 4; ++ky) {
                int idx = (kx*x + 2*ky*y) & 31;
                gre[kx*4+ky] += v * c32[idx];
                gim[kx*4+ky] -= v * s32[idx];
            }
        }
    }
    #pragma unroll
    for (int m = 0; m < 16; ++m) {
        for (int off = 32; off > 0; off >>= 1) {
            gre[m] += __shfl_xor(gre[m], off, 64);
            gim[m] += __shfl_xor(gim[m], off, 64);
        }
    }
    if (lane == 0) {
        #pragma unroll
        for (int m = 0; m < 16; ++m) { wsum[wave][m] = gre[m]; wsum[wave][16+m] = gim[m]; }
    }
    __syncthreads();
    if (t < 32) {
        float s = wsum[0][t] + wsum[1][t] + wsum[2][t] + wsum[3][t];
        if (t < 16) Gre[t] = s; else Gim[t-16] = s;
    }

    for (int idx = t; idx < 512; idx += 256) {
        int o = idx >> 4, m = idx & 15;
        float ar = 0.f, ai = 0.f;
        for (int ii = 0; ii < WIDTH; ++ii) {
            float lw = lift_W[ii];
            ar += lw * spec_Wr[ii*512 + o*16 + m];
            ai += lw * spec_Wi[ii*512 + o*16 + m];
        }
        Arr[o][m] = ar; Aii[o][m] = ai;
    }
    if (t < 32) {
        float br = 0.f, bi = 0.f, pl = 0.f, cb = 0.f;
        for (int ii = 0; ii < WIDTH; ++ii) {
            float lb = lift_b[ii];
            br += lb * spec_Wr[ii*512 + t*16 + 0];
            bi += lb * spec_Wi[ii*512 + t*16 + 0];
            pl += lift_W[ii] * pw_W[ii*WIDTH + t];
            cb += lb * pw_W[ii*WIDTH + t];
        }
        Brr[t] = br; Bii[t] = bi;
        pwl[t] = pl;
        cb0[t] = cb + pw_b[t];
    }
    __syncthreads();

    for (int idx = t; idx < 512; idx += 256) {
        int o = idx >> 4, m = idx & 15;
        float gr = Gre[m], gi = Gim[m];
        float ar = Arr[o][m], ai = Aii[o][m];
        float lr = gr*ar - gi*ai;
        float li = gr*ai + gi*ar;
        if (m == 0) { lr += 512.f * Brr[o]; li += 512.f * Bii[o]; }
        lowr[o][m] = lr; lowi[o][m] = li;
    }
    __syncthreads();

    const int o  = t >> 3;
    const int xg = t & 7;
    const float plo = pwl[o], cbo = cb0[o];
    float acc = 0.f;
    const float inv32 = 1.0f/32.0f, inv16 = 1.0f/16.0f;
    for (int xi = 0; xi < 4; ++xi) {
        int x = xg*4 + xi;
        float Tre[4], Tim[4];
        #pragma unroll
        for (int ky = 0; ky < 4; ++ky) { Tre[ky] = 0.f; Tim[ky] = 0.f; }
        #pragma unroll
        for (int kx = 0; kx < 4; ++kx) {
            int idx = (kx*x) & 31;
            float c = c32[idx], s = s32[idx];
            #pragma unroll
            for (int ky = 0; ky < 4; ++ky) {
                float lr = lowr[o][kx*4+ky], li = lowi[o][kx*4+ky];
                Tre[ky] += lr*c - li*s;
                Tim[ky] += lr*s + li*c;
            }
        }
        #pragma unroll
        for (int ky = 0; ky < 4; ++ky) { Tre[ky] *= inv32; Tim[ky] *= inv32; }
        for (int y = 0; y < 16; ++y) {
            float hsv = Tre[0];
            #pragma unroll
            for (int ky = 1; ky < 4; ++ky) {
                int idx = (2*ky*y) & 31;
                hsv += 2.f*(Tre[ky]*c32[idx] - Tim[ky]*s32[idx]);
            }
            hsv *= inv16;
            float z = hsv + nf[x*16 + y]*plo + cbo;
            acc += tanhf(z);
        }
    }
    acc += __shfl_down(acc, 4, 8);
    acc += __shfl_down(acc, 2, 8);
    acc += __shfl_down(acc, 1, 8);
    if ((t & 7) == 0) pooled_g[b*WIDTH + o] = acc * (1.0f/512.0f);
}

// ---------------------------------------------------------------------------
// Kernel 2: r-major gathered build (proj_W row segment in registers, reused
// across 256 samples). Writes A_ws coalesced.
// ---------------------------------------------------------------------------
__global__ __launch_bounds__(128) void build_kernel(
    const float* __restrict__ M_base,
    const float* __restrict__ proj_W,
    const float* __restrict__ proj_b,
    const float* __restrict__ pooled_g,
    const signed char* __restrict__ pos_g,
    float* __restrict__ A_ws)
{
    __shared__ float pooled_l[256*WIDTH];   // 32 KB
    __shared__ signed char posl[256];

    const int r  = blockIdx.x >> 2;
    const int b0 = (blockIdx.x & 3) * 256;
    const int j  = threadIdx.x;

    {
        const float4* src = (const float4*)(pooled_g + (size_t)b0*WIDTH);
        float4* dst = (float4*)pooled_l;
        for (int idx = j; idx < 256*WIDTH/4; idx += 128) dst[idx] = src[idx];
        if (j < 64) ((int*)posl)[j] = ((const int*)(pos_g + (size_t)r*BB + b0))[j];
    }

    float wj[WIDTH];
    #pragma unroll
    for (int o = 0; o < WIDTH; ++o) wj[o] = proj_W[(size_t)o*TOTAL + r*NF + j];
    const float base = M_base[r*NF + j] + proj_b[r*NF + j];
    __syncthreads();

    for (int bb = 0; bb < 256; ++bb) {
        int pos = posl[bb];
        if (pos < 0) continue;
        const float* pl = &pooled_l[bb*WIDTH];
        float acc = base;
        #pragma unroll
        for (int o = 0; o < WIDTH; ++o) acc += pl[o]*wj[o];
        A_ws[((size_t)(b0+bb)*NF + pos)*NF + j] = acc;
    }
}

// ---------------------------------------------------------------------------
// Kernel 3: rank-8 blocked LU, A in registers, dedicated pivot wave, R10's
// proven 3-phase/panel structure -- but 16 panels => 48 barriers (was 96).
// Pivot rows are RETIRED, not replaced (their trailing values are never read:
// diag is captured at selection, future panels mask done rows, Raw uses
// pre-panel values) -- no M^{-1} materialization at all.
// Output planar: out[b] = logabs, out[BB+b] = 0 or pi.
// ---------------------------------------------------------------------------
__global__ __launch_bounds__(576) void lu_kernel(
    const float* __restrict__ A_ws,
    float* __restrict__ out)
{
    __shared__ __align__(16) float pcolA[128*4];  // panel cols 0-3
    __shared__ __align__(16) float pcolB[128*4];  // panel cols 4-7
    __shared__ __align__(16) float Raw[8*128];    // pre-panel pivot rows
    __shared__ __align__(16) float coefb[128*8];  // composite coefs per row
    __shared__ float pvbuf[128];
    __shared__ int   pivseq[128];
    __shared__ int   pr8[8];

    const int b = blockIdx.x;
    const int t = threadIdx.x;
    const int lane = t & 63;
    const int u = t - 64;
    const int i = u & 127;
    const int q = (u >> 7) & 3;

    float4 Areg[8];
    if (t >= 64) {
        const float4* src = (const float4*)(A_ws + (size_t)b*(NF*NF) + i*NF + q*32);
        #pragma unroll
        for (int g = 0; g < 8; ++g) Areg[g] = src[g];
        if (q == 0) {
            *((float4*)&pcolA[i*4]) = Areg[0];
            *((float4*)&pcolB[i*4]) = Areg[1];
        }
    }
    bool done_i = false;
    bool done0 = false, done1 = false;
    __syncthreads();

    for (int p = 0; p < 16; ++p) {
        // ---------- phase 1: pivot 8 panel columns (wave 0) ----------
        if (t < 64) {
            float4 a0v = *((const float4*)&pcolA[lane*4]);
            float4 b0v = *((const float4*)&pcolB[lane*4]);
            float4 a1v = *((const float4*)&pcolA[lane*4 + 256]);
            float4 b1v = *((const float4*)&pcolB[lane*4 + 256]);
            float v0[8] = { a0v.x,a0v.y,a0v.z,a0v.w, b0v.x,b0v.y,b0v.z,b0v.w };
            float v1[8] = { a1v.x,a1v.y,a1v.z,a1v.w, b1v.x,b1v.y,b1v.z,b1v.w };
            float lr0[8], lr1[8];
            int   prreg[8];

            #pragma unroll
            for (int k = 0; k < 8; ++k) {
                unsigned aa0 = __float_as_uint(v0[k]) & 0x7fffffffu;
                unsigned aa1 = __float_as_uint(v1[k]) & 0x7fffffffu;
                unsigned key0 = done0 ? 0u : ((aa0 & 0xffffff80u) | (unsigned)lane);
                unsigned key1 = done1 ? 0u : ((aa1 & 0xffffff80u) | (unsigned)(lane + 64));
                unsigned key = (key1 > key0) ? key1 : key0;
                DPP_UMAX(key, 0x111, 0xf);   // row_shr:1
                DPP_UMAX(key, 0x112, 0xf);   // row_shr:2
                DPP_UMAX(key, 0x114, 0xf);   // row_shr:4
                DPP_UMAX(key, 0x118, 0xf);   // row_shr:8
                DPP_UMAX(key, 0x142, 0xa);   // row_bcast:15
                DPP_UMAX(key, 0x143, 0xc);   // row_bcast:31
                const unsigned best = (unsigned)__builtin_amdgcn_readlane((int)key, 63);
                const int row = (int)(best & 127u);
                const int lw  = row & 63;
                const bool lowh = (row < 64);
                const float pv = lowh ? readlanef(v0[k], lw) : readlanef(v1[k], lw);
                prreg[k] = row;
                const float inv = 1.0f / pv;
                float l0 = (done0 || row == lane)      ? 0.f : v0[k] * inv;
                float l1 = (done1 || row == lane + 64) ? 0.f : v1[k] * inv;
                lr0[k] = l0; lr1[k] = l1;
                if (row == lane)      done0 = true;
                if (row == lane + 64) done1 = true;
                #pragma unroll
                for (int j = 0; j < 8; ++j) if (j > k) {
                    float ukj = lowh ? readlanef(v0[j], lw) : readlanef(v1[j], lw);
                    v0[j] -= l0 * ukj;
                    v1[j] -= l1 * ukj;
                }
                if (lane == 0) { pivseq[8*p+k] = row; pvbuf[8*p+k] = pv; }
            }

            // Lt[sp][s] (sp>s): l of pivot-row sp at step s, via readlane
            float Lt[8][8];
            #pragma unroll
            for (int sp = 1; sp < 8; ++sp) {
                #pragma unroll
                for (int s = 0; s < 8; ++s) if (s < sp) {
                    Lt[sp][s] = (prreg[sp] < 64) ? readlanef(lr0[s], prreg[sp])
                                                 : readlanef(lr1[s], prreg[sp] - 64);
                }
            }
            // composite coefs: c = -(l . M), M=(I+Lt)^{-1}; back-substitution
            // c[s] = -l[s] - sum_{sp>s} c[sp]*Lt[sp][s]
            {
                float c[8];
                #pragma unroll
                for (int s = 7; s >= 0; --s) {
                    float acc = -lr0[s];
                    #pragma unroll
                    for (int sp = 7; sp > 0; --sp) if (sp > s) acc -= c[sp]*Lt[sp][s];
                    c[s] = acc;
                }
                *((float4*)&coefb[lane*8])     = make_float4(c[0],c[1],c[2],c[3]);
                *((float4*)&coefb[lane*8 + 4]) = make_float4(c[4],c[5],c[6],c[7]);
            }
            {
                float d[8];
                #pragma unroll
                for (int s = 7; s >= 0; --s) {
                    float acc = -lr1[s];
                    #pragma unroll
                    for (int sp = 7; sp > 0; --sp) if (sp > s) acc -= d[sp]*Lt[sp][s];
                    d[s] = acc;
                }
                *((float4*)&coefb[(lane+64)*8])     = make_float4(d[0],d[1],d[2],d[3]);
                *((float4*)&coefb[(lane+64)*8 + 4]) = make_float4(d[4],d[5],d[6],d[7]);
            }
            if (lane == 0) {
                pr8[0]=prreg[0]; pr8[1]=prreg[1]; pr8[2]=prreg[2]; pr8[3]=prreg[3];
                pr8[4]=prreg[4]; pr8[5]=prreg[5]; pr8[6]=prreg[6]; pr8[7]=prreg[7];
            }
        }
        __syncthreads();   // barrier A: pr8/coefb/pivseq ready

        // ---------- phase 2: pivot-row owners publish Raw (pre-panel) ----------
        int fp = -1;
        if (t >= 64) {
            #pragma unroll
            for (int s = 0; s < 8; ++s) if (i == pr8[s]) fp = s;
            if (fp >= 0) {
                #pragma unroll
                for (int g = 0; g < 8; ++g)
                    *((float4*)&Raw[fp*128 + q*32 + g*4]) = Areg[g];
            }
        }
        __syncthreads();   // barrier B: Raw ready

        // ---------- phase 3: rank-8 update (non-retired rows) + pcol(p+1) ----------
        if (t >= 64) {
            if (fp >= 0) {
                done_i = true;   // retired; trailing values never read again
            } else if (!done_i) {
                const float4 cfA = *((const float4*)&coefb[i*8]);
                const float4 cfB = *((const float4*)&coefb[i*8 + 4]);
                const float cs[8] = { cfA.x, cfA.y, cfA.z, cfA.w,
                                      cfB.x, cfB.y, cfB.z, cfB.w };
                #pragma unroll
                for (int g = 0; g < 8; ++g) {
                    const int G = q*8 + g;
                    if (G > 2*p + 1) {
                        const int cbase = G*4;
                        float4 own = Areg[g];
                        #pragma unroll
                        for (int s = 0; s < 8; ++s) {
                            const float4 rv = *((const float4*)&Raw[s*128 + cbase]);
                            own.x += cs[s]*rv.x; own.y += cs[s]*rv.y;
                            own.z += cs[s]*rv.z; own.w += cs[s]*rv.w;
                        }
                        Areg[g] = own;
                        if (p < 15) {
                            if (G == 2*p + 2) *((float4*)&pcolA[i*4]) = own;
                            if (G == 2*p + 3) *((float4*)&pcolB[i*4]) = own;
                        }
                    }
                }
            }
        }
        __syncthreads();   // barrier C: Areg stable + pcol(p+1) ready
    }

    // ---------- logabs + sign (wave 0) ----------
    if (t < 64) {
        float d0 = pvbuf[lane], d1 = pvbuf[lane + 64];
        int   ps0 = pivseq[lane], ps1 = pivseq[lane + 64];
        float ls = logf(fabsf(d0)) + logf(fabsf(d1));
        int neg = ((d0 < 0.f) ? 1 : 0) ^ ((d1 < 0.f) ? 1 : 0);
        #pragma unroll
        for (int off = 32; off > 0; off >>= 1) {
            ls  += __shfl_xor(ls,  off, 64);
            neg ^= __shfl_xor(neg, off, 64);
        }
        unsigned long long vis0 = 0ull, vis1 = 0ull;
        int trans = 0;
        for (int k = 0; k < 128; ++k) {
            bool vk = (k < 64) ? ((vis0 >> k) & 1ull) : ((vis1 >> (k - 64)) & 1ull);
            if (!vk) {
                int j = k, len = 0;
                while (true) {
                    bool vj = (j < 64) ? ((vis0 >> j) & 1ull) : ((vis1 >> (j - 64)) & 1ull);
                    if (vj) break;
                    if (j < 64) vis0 |= (1ull << j); else vis1 |= (1ull << (j - 64));
                    j = (j < 64) ? __builtin_amdgcn_readlane(ps0, j)
                                 : __builtin_amdgcn_readlane(ps1, j - 64);
                    ++len;
                }
                trans += len - 1;
            }
        }
        if (lane == 0) {
            int parity = (neg ^ (trans & 1)) & 1;
            out[b]      = ls;
            out[BB + b] = parity ? (float)M_PI : 0.0f;
        }
    }
}

// ---------------------------------------------------------------------------
extern "C" void kernel_launch(void* const* d_in, const int* in_sizes, int n_in,
                              void* d_out, int out_size, void* d_ws, size_t ws_size,
                              hipStream_t stream) {
    const int*   n       = (const int*)  d_in[0];
    const float* M_base  = (const float*)d_in[1];
    const float* lift_W  = (const float*)d_in[2];
    const float* lift_b  = (const float*)d_in[3];
    const float* spec_Wr = (const float*)d_in[4];
    const float* spec_Wi = (const float*)d_in[5];
    const float* pw_W    = (const float*)d_in[6];
    const float* pw_b    = (const float*)d_in[7];
    const float* proj_W  = (const float*)d_in[8];
    const float* proj_b  = (const float*)d_in[9];

    // ws layout: pooled 128KB | pos 512KB | (align 1MB) A_ws 64MB
    float*       pooled = (float*)d_ws;
    signed char* pos    = (signed char*)((char*)d_ws + 128*1024);
    float*       A_ws   = (float*)((char*)d_ws + (1 << 20));

    fno_pooled_kernel<<<BB, 256, 0, stream>>>(n, lift_W, lift_b, spec_Wr, spec_Wi,
                                              pw_W, pw_b, pooled, pos);
    build_kernel<<<SIZE*4, 128, 0, stream>>>(M_base, proj_W, proj_b, pooled, pos, A_ws);
    lu_kernel<<<BB, 576, 0, stream>>>(A_ws, (float*)d_out);
}

// Round 13
// 419.782 us; speedup vs baseline: 1.5361x; 1.0120x over previous
//
#include <hip/hip_runtime.h>
#include <math.h>

#ifndef M_PI
#define M_PI 3.14159265358979323846
#endif

#define BB 1024
#define SIZE 512
#define NF 128
#define WIDTH 32
#define TOTAL (SIZE*NF)

// DPP-based unsigned max reduce step (VALU latency, no LDS pipe)
#define DPP_UMAX(x, ctrl, rmask) { \
    unsigned _t = (unsigned)__builtin_amdgcn_update_dpp(0, (int)(x), (ctrl), (rmask), 0xf, false); \
    if (_t > (x)) (x) = _t; }

__device__ __forceinline__ float readlanef(float x, int l) {
    return __int_as_float(__builtin_amdgcn_readlane(__float_as_int(x), l));
}

// Swizzled LDS layout: element (i, 4G+j) at float index i*128 + ((G^(i&7))<<2) + j.
// Fixed-G column access across rows: each 8-lane packet covers all 32 banks (b128
// conflict-free); broadcast reads (same addr) free.
__device__ __forceinline__ int agrp(int i, int G) {
    return i*128 + ((G ^ (i & 7)) << 2);
}

// ---------------------------------------------------------------------------
// Kernel 1: per-sample FNO frontend -> pooled[b][32], pos[r][b] (gather map)
// ---------------------------------------------------------------------------
__global__ __launch_bounds__(256) void fno_pooled_kernel(
    const int*   __restrict__ n,
    const float* __restrict__ lift_W,
    const float* __restrict__ lift_b,
    const float* __restrict__ spec_Wr,
    const float* __restrict__ spec_Wi,
    const float* __restrict__ pw_W,
    const float* __restrict__ pw_b,
    float* __restrict__ pooled_g,
    signed char* __restrict__ pos_g)
{
    __shared__ float nf[SIZE];
    __shared__ float c32[32], s32[32];
    __shared__ float Gre[16], Gim[16];
    __shared__ float wsum[4][32];
    __shared__ float Arr[WIDTH][16], Aii[WIDTH][16];
    __shared__ float lowr[WIDTH][16], lowi[WIDTH][16];
    __shared__ float pwl[WIDTH], cb0[WIDTH];
    __shared__ float Brr[WIDTH], Bii[WIDTH];

    const int b = blockIdx.x;
    const int t = threadIdx.x;
    const int lane = t & 63;
    const int wave = t >> 6;

    if (t < 32) {
        float ang = (float)t * (2.0f * (float)M_PI / 32.0f);
        c32[t] = cosf(ang);
        s32[t] = sinf(ang);
    }
    for (int p = t; p < SIZE; p += 256) nf[p] = (float)n[b*SIZE + p];
    __syncthreads();

    if (wave == 0) {
        int base = 0;
        for (int c = 0; c < 8; ++c) {
            int p = c*64 + lane;
            bool occ = (nf[p] != 0.0f);
            unsigned long long mask = __ballot(occ);
            int prefix = __popcll(mask & ((1ull << lane) - 1ull));
            int pos = base + prefix;
            pos_g[(size_t)p*BB + b] = (occ && pos < NF) ? (signed char)pos : (signed char)-1;
            base += __popcll(mask);
        }
    }

    float gre[16], gim[16];
    #pragma unroll
    for (int m = 0; m < 16; ++m) { gre[m] = 0.f; gim[m] = 0.f; }
    for (int p = t; p < SIZE; p += 256) {
        float v = nf[p];
        int x = p >> 4, y = p & 15;
        #pragma unroll
        for (int kx = 0; kx < 4; ++kx) {
            #pragma unroll
            for (int ky = 0; ky < 4; ++ky) {
                int idx = (kx*x + 2*ky*y) & 31;
                gre[kx*4+ky] += v * c32[idx];
                gim[kx*4+ky] -= v * s32[idx];
            }
        }
    }
    #pragma unroll
    for (int m = 0; m < 16; ++m) {
        for (int off = 32; off > 0; off >>= 1) {
            gre[m] += __shfl_xor(gre[m], off, 64);
            gim[m] += __shfl_xor(gim[m], off, 64);
        }
    }
    if (lane == 0) {
        #pragma unroll
        for (int m = 0; m < 16; ++m) { wsum[wave][m] = gre[m]; wsum[wave][16+m] = gim[m]; }
    }
    __syncthreads();
    if (t < 32) {
        float s = wsum[0][t] + wsum[1][t] + wsum[2][t] + wsum[3][t];
        if (t < 16) Gre[t] = s; else Gim[t-16] = s;
    }

    for (int idx = t; idx < 512; idx += 256) {
        int o = idx >> 4, m = idx & 15;
        float ar = 0.f, ai = 0.f;
        for (int ii = 0; ii < WIDTH; ++ii) {
            float lw = lift_W[ii];
            ar += lw * spec_Wr[ii*512 + o*16 + m];
            ai += lw * spec_Wi[ii*512 + o*16 + m];
        }
        Arr[o][m] = ar; Aii[o][m] = ai;
    }
    if (t < 32) {
        float br = 0.f, bi = 0.f, pl = 0.f, cb = 0.f;
        for (int ii = 0; ii < WIDTH; ++ii) {
            float lb = lift_b[ii];
            br += lb * spec_Wr[ii*512 + t*16 + 0];
            bi += lb * spec_Wi[ii*512 + t*16 + 0];
            pl += lift_W[ii] * pw_W[ii*WIDTH + t];
            cb += lb * pw_W[ii*WIDTH + t];
        }
        Brr[t] = br; Bii[t] = bi;
        pwl[t] = pl;
        cb0[t] = cb + pw_b[t];
    }
    __syncthreads();

    for (int idx = t; idx < 512; idx += 256) {
        int o = idx >> 4, m = idx & 15;
        float gr = Gre[m], gi = Gim[m];
        float ar = Arr[o][m], ai = Aii[o][m];
        float lr = gr*ar - gi*ai;
        float li = gr*ai + gi*ar;
        if (m == 0) { lr += 512.f * Brr[o]; li += 512.f * Bii[o]; }
        lowr[o][m] = lr; lowi[o][m] = li;
    }
    __syncthreads();

    const int o  = t >> 3;
    const int xg = t & 7;
    const float plo = pwl[o], cbo = cb0[o];
    float acc = 0.f;
    const float inv32 = 1.0f/32.0f, inv16 = 1.0f/16.0f;
    for (int xi = 0; xi < 4; ++xi) {
        int x = xg*4 + xi;
        float Tre[4], Tim[4];
        #pragma unroll
        for (int ky = 0; ky < 4; ++ky) { Tre[ky] = 0.f; Tim[ky] = 0.f; }
        #pragma unroll
        for (int kx = 0; kx < 4; ++kx) {
            int idx = (kx*x) & 31;
            float c = c32[idx], s = s32[idx];
            #pragma unroll
            for (int ky = 0; ky < 4; ++ky) {
                float lr = lowr[o][kx*4+ky], li = lowi[o][kx*4+ky];
                Tre[ky] += lr*c - li*s;
                Tim[ky] += lr*s + li*c;
            }
        }
        #pragma unroll
        for (int ky = 0; ky < 4; ++ky) { Tre[ky] *= inv32; Tim[ky] *= inv32; }
        for (int y = 0; y < 16; ++y) {
            float hsv = Tre[0];
            #pragma unroll
            for (int ky = 1; ky < 4; ++ky) {
                int idx = (2*ky*y) & 31;
                hsv += 2.f*(Tre[ky]*c32[idx] - Tim[ky]*s32[idx]);
            }
            hsv *= inv16;
            float z = hsv + nf[x*16 + y]*plo + cbo;
            acc += tanhf(z);
        }
    }
    acc += __shfl_down(acc, 4, 8);
    acc += __shfl_down(acc, 2, 8);
    acc += __shfl_down(acc, 1, 8);
    if ((t & 7) == 0) pooled_g[b*WIDTH + o] = acc * (1.0f/512.0f);
}

// ---------------------------------------------------------------------------
// Kernel 2: r-major gathered build (proj_W row segment in registers, reused
// across 256 samples). Writes A_ws coalesced.
// ---------------------------------------------------------------------------
__global__ __launch_bounds__(128) void build_kernel(
    const float* __restrict__ M_base,
    const float* __restrict__ proj_W,
    const float* __restrict__ proj_b,
    const float* __restrict__ pooled_g,
    const signed char* __restrict__ pos_g,
    float* __restrict__ A_ws)
{
    __shared__ float pooled_l[256*WIDTH];   // 32 KB
    __shared__ signed char posl[256];

    const int r  = blockIdx.x >> 2;
    const int b0 = (blockIdx.x & 3) * 256;
    const int j  = threadIdx.x;

    {
        const float4* src = (const float4*)(pooled_g + (size_t)b0*WIDTH);
        float4* dst = (float4*)pooled_l;
        for (int idx = j; idx < 256*WIDTH/4; idx += 128) dst[idx] = src[idx];
        if (j < 64) ((int*)posl)[j] = ((const int*)(pos_g + (size_t)r*BB + b0))[j];
    }

    float wj[WIDTH];
    #pragma unroll
    for (int o = 0; o < WIDTH; ++o) wj[o] = proj_W[(size_t)o*TOTAL + r*NF + j];
    const float base = M_base[r*NF + j] + proj_b[r*NF + j];
    __syncthreads();

    for (int bb = 0; bb < 256; ++bb) {
        int pos = posl[bb];
        if (pos < 0) continue;
        const float* pl = &pooled_l[bb*WIDTH];
        float acc = base;
        #pragma unroll
        for (int o = 0; o < WIDTH; ++o) acc += pl[o]*wj[o];
        A_ws[((size_t)(b0+bb)*NF + pos)*NF + j] = acc;
    }
}

// ---------------------------------------------------------------------------
// Kernel 3: paired-sample rank-8 LU, matrices in LDS (2 x 64 KB, swizzled).
// 512 threads: wave 0 = pivot wave; waves 1-7 = update waves.
// Phase 2p:   pivot_A(p) || update_B(p-1);  Phase 2p+1: pivot_B(p) || update_A(p).
// The serial pivot chain of one sample hides under the other's rank-8 update.
// Pivot rows are retired (never rewritten) -> pre-panel values read in place;
// retired rows have all-zero composite coefs -> zero-check skip, no flags.
// Output planar: out[b] = logabs, out[BB+b] = 0 or pi.
// ---------------------------------------------------------------------------
__global__ __launch_bounds__(512) void lu_kernel(
    const float* __restrict__ A_ws,
    float* __restrict__ out)
{
    __shared__ __align__(16) float Amat[2][NF*NF];   // 128 KB
    __shared__ __align__(16) float coefs[2][NF*8];   // 8 KB
    __shared__ float pvbuf[2][NF];
    __shared__ int   pivseq[2][NF];
    __shared__ int   pr8s[2][8];

    const int t = threadIdx.x;
    const int lane = t & 63;
    const int wave = t >> 6;
    const int bA = blockIdx.x * 2;

    // ---- stage both matrices into LDS (swizzled), coalesced global reads ----
    {
        const float4* gsrc = (const float4*)(A_ws + (size_t)bA*(NF*NF));
        for (int it = t; it < 2*4096; it += 512) {
            const int smp  = it >> 12;
            const int rest = it & 4095;
            const int i = rest >> 5, G = rest & 31;
            float4 v = gsrc[it];
            *((float4*)&Amat[smp][agrp(i, G)]) = v;
        }
    }
    // pivot-wave per-lane retire masks, per sample
    bool dA0 = false, dA1 = false, dB0 = false, dB1 = false;
    __syncthreads();

    for (int ph = 0; ph < 32; ++ph) {
        const int s = ph & 1;        // 0: pivot A, 1: pivot B
        const int p = ph >> 1;

        if (wave == 0) {
            // ================= pivot(sample s, panel p) =================
            float* Am = Amat[s];
            bool& done0 = (s == 0) ? dA0 : dB0;
            bool& done1 = (s == 0) ? dA1 : dB1;

            float4 a0v = *((const float4*)&Am[agrp(lane,      2*p)]);
            float4 b0v = *((const float4*)&Am[agrp(lane,      2*p+1)]);
            float4 a1v = *((const float4*)&Am[agrp(lane + 64, 2*p)]);
            float4 b1v = *((const float4*)&Am[agrp(lane + 64, 2*p+1)]);
            float v0[8] = { a0v.x,a0v.y,a0v.z,a0v.w, b0v.x,b0v.y,b0v.z,b0v.w };
            float v1[8] = { a1v.x,a1v.y,a1v.z,a1v.w, b1v.x,b1v.y,b1v.z,b1v.w };
            float lr0[8], lr1[8];
            int   prreg[8];

            #pragma unroll
            for (int k = 0; k < 8; ++k) {
                unsigned aa0 = __float_as_uint(v0[k]) & 0x7fffffffu;
                unsigned aa1 = __float_as_uint(v1[k]) & 0x7fffffffu;
                unsigned key0 = done0 ? 0u : ((aa0 & 0xffffff80u) | (unsigned)lane);
                unsigned key1 = done1 ? 0u : ((aa1 & 0xffffff80u) | (unsigned)(lane + 64));
                unsigned key = (key1 > key0) ? key1 : key0;
                DPP_UMAX(key, 0x111, 0xf);   // row_shr:1
                DPP_UMAX(key, 0x112, 0xf);   // row_shr:2
                DPP_UMAX(key, 0x114, 0xf);   // row_shr:4
                DPP_UMAX(key, 0x118, 0xf);   // row_shr:8
                DPP_UMAX(key, 0x142, 0xa);   // row_bcast:15
                DPP_UMAX(key, 0x143, 0xc);   // row_bcast:31
                const unsigned best = (unsigned)__builtin_amdgcn_readlane((int)key, 63);
                const int row = (int)(best & 127u);
                const int lw  = row & 63;
                const bool lowh = (row < 64);
                const float pv = lowh ? readlanef(v0[k], lw) : readlanef(v1[k], lw);
                prreg[k] = row;
                const float inv = 1.0f / pv;
                float l0 = (done0 || row == lane)      ? 0.f : v0[k] * inv;
                float l1 = (done1 || row == lane + 64) ? 0.f : v1[k] * inv;
                lr0[k] = l0; lr1[k] = l1;
                if (row == lane)      done0 = true;
                if (row == lane + 64) done1 = true;
                #pragma unroll
                for (int j = 0; j < 8; ++j) if (j > k) {
                    float ukj = lowh ? readlanef(v0[j], lw) : readlanef(v1[j], lw);
                    v0[j] -= l0 * ukj;
                    v1[j] -= l1 * ukj;
                }
                if (lane == 0) { pivseq[s][8*p+k] = row; pvbuf[s][8*p+k] = pv; }
            }

            // Lt[sp][s2] (sp>s2): l of pivot-row sp at step s2, via readlane
            float Lt[8][8];
            #pragma unroll
            for (int sp = 1; sp < 8; ++sp) {
                #pragma unroll
                for (int s2 = 0; s2 < 8; ++s2) if (s2 < sp) {
                    Lt[sp][s2] = (prreg[sp] < 64) ? readlanef(lr0[s2], prreg[sp])
                                                  : readlanef(lr1[s2], prreg[sp] - 64);
                }
            }
            // composite coefs by back-substitution: c[s2] = -l[s2] - sum_{sp>s2} c[sp]*Lt[sp][s2]
            {
                float c[8];
                #pragma unroll
                for (int s2 = 7; s2 >= 0; --s2) {
                    float acc = -lr0[s2];
                    #pragma unroll
                    for (int sp = 7; sp > 0; --sp) if (sp > s2) acc -= c[sp]*Lt[sp][s2];
                    c[s2] = acc;
                }
                *((float4*)&coefs[s][lane*8])     = make_float4(c[0],c[1],c[2],c[3]);
                *((float4*)&coefs[s][lane*8 + 4]) = make_float4(c[4],c[5],c[6],c[7]);
            }
            {
                float d[8];
                #pragma unroll
                for (int s2 = 7; s2 >= 0; --s2) {
                    float acc = -lr1[s2];
                    #pragma unroll
                    for (int sp = 7; sp > 0; --sp) if (sp > s2) acc -= d[sp]*Lt[sp][s2];
                    d[s2] = acc;
                }
                *((float4*)&coefs[s][(lane+64)*8])     = make_float4(d[0],d[1],d[2],d[3]);
                *((float4*)&coefs[s][(lane+64)*8 + 4]) = make_float4(d[4],d[5],d[6],d[7]);
            }
            if (lane == 0) {
                #pragma unroll
                for (int k = 0; k < 8; ++k) pr8s[s][k] = prreg[k];
            }
        } else {
            // ================= update(sample s^1, panel pu) =================
            const int u  = s ^ 1;
            const int pu = (s == 0) ? p - 1 : p;
            if (pu >= 0) {
                float* Am = Amat[u];
                const int Gmin = 2*pu + 2;
                if (Gmin < 32) {
                    const int row0 = lane, row1 = lane + 64;
                    const float4 c0a = *((const float4*)&coefs[u][row0*8]);
                    const float4 c0b = *((const float4*)&coefs[u][row0*8 + 4]);
                    const float4 c1a = *((const float4*)&coefs[u][row1*8]);
                    const float4 c1b = *((const float4*)&coefs[u][row1*8 + 4]);
                    const bool sk0 = (c0a.x==0.f && c0a.y==0.f && c0a.z==0.f && c0a.w==0.f &&
                                      c0b.x==0.f && c0b.y==0.f && c0b.z==0.f && c0b.w==0.f);
                    const bool sk1 = (c1a.x==0.f && c1a.y==0.f && c1a.z==0.f && c1a.w==0.f &&
                                      c1b.x==0.f && c1b.y==0.f && c1b.z==0.f && c1b.w==0.f);
                    if (!(sk0 && sk1)) {
                        int pr0 = pr8s[u][0], pr1 = pr8s[u][1], pr2 = pr8s[u][2], pr3 = pr8s[u][3];
                        int pr4_ = pr8s[u][4], pr5 = pr8s[u][5], pr6 = pr8s[u][6], pr7 = pr8s[u][7];
                        for (int G = Gmin + (wave - 1); G < 32; G += 7) {
                            float4 own0, own1;
                            if (!sk0) own0 = *((const float4*)&Am[agrp(row0, G)]);
                            if (!sk1) own1 = *((const float4*)&Am[agrp(row1, G)]);
                            {   // pivot rows 0-3
                                const float4 r0 = *((const float4*)&Am[agrp(pr0, G)]);
                                const float4 r1 = *((const float4*)&Am[agrp(pr1, G)]);
                                const float4 r2 = *((const float4*)&Am[agrp(pr2, G)]);
                                const float4 r3 = *((const float4*)&Am[agrp(pr3, G)]);
                                if (!sk0) {
                                    own0.x += c0a.x*r0.x + c0a.y*r1.x + c0a.z*r2.x + c0a.w*r3.x;
                                    own0.y += c0a.x*r0.y + c0a.y*r1.y + c0a.z*r2.y + c0a.w*r3.y;
                                    own0.z += c0a.x*r0.z + c0a.y*r1.z + c0a.z*r2.z + c0a.w*r3.z;
                                    own0.w += c0a.x*r0.w + c0a.y*r1.w + c0a.z*r2.w + c0a.w*r3.w;
                                }
                                if (!sk1) {
                                    own1.x += c1a.x*r0.x + c1a.y*r1.x + c1a.z*r2.x + c1a.w*r3.x;
                                    own1.y += c1a.x*r0.y + c1a.y*r1.y + c1a.z*r2.y + c1a.w*r3.y;
                                    own1.z += c1a.x*r0.z + c1a.y*r1.z + c1a.z*r2.z + c1a.w*r3.z;
                                    own1.w += c1a.x*r0.w + c1a.y*r1.w + c1a.z*r2.w + c1a.w*r3.w;
                                }
                            }
                            {   // pivot rows 4-7
                                const float4 r0 = *((const float4*)&Am[agrp(pr4_, G)]);
                                const float4 r1 = *((const float4*)&Am[agrp(pr5, G)]);
                                const float4 r2 = *((const float4*)&Am[agrp(pr6, G)]);
                                const float4 r3 = *((const float4*)&Am[agrp(pr7, G)]);
                                if (!sk0) {
                                    own0.x += c0b.x*r0.x + c0b.y*r1.x + c0b.z*r2.x + c0b.w*r3.x;
                                    own0.y += c0b.x*r0.y + c0b.y*r1.y + c0b.z*r2.y + c0b.w*r3.y;
                                    own0.z += c0b.x*r0.z + c0b.y*r1.z + c0b.z*r2.z + c0b.w*r3.z;
                                    own0.w += c0b.x*r0.w + c0b.y*r1.w + c0b.z*r2.w + c0b.w*r3.w;
                                }
                                if (!sk1) {
                                    own1.x += c1b.x*r0.x + c1b.y*r1.x + c1b.z*r2.x + c1b.w*r3.x;
                                    own1.y += c1b.x*r0.y + c1b.y*r1.y + c1b.z*r2.y + c1b.w*r3.y;
                                    own1.z += c1b.x*r0.z + c1b.y*r1.z + c1b.z*r2.z + c1b.w*r3.z;
                                    own1.w += c1b.x*r0.w + c1b.y*r1.w + c1b.z*r2.w + c1b.w*r3.w;
                                }
                            }
                            if (!sk0) *((float4*)&Am[agrp(row0, G)]) = own0;
                            if (!sk1) *((float4*)&Am[agrp(row1, G)]) = own1;
                        }
                    }
                }
            }
        }
        __syncthreads();
    }

    // ================= logabs + sign, both samples (wave 0) =================
    if (wave == 0) {
        for (int s = 0; s < 2; ++s) {
            float d0 = pvbuf[s][lane], d1 = pvbuf[s][lane + 64];
            int   ps0 = pivseq[s][lane], ps1 = pivseq[s][lane + 64];
            float ls = logf(fabsf(d0)) + logf(fabsf(d1));
            int neg = ((d0 < 0.f) ? 1 : 0) ^ ((d1 < 0.f) ? 1 : 0);
            #pragma unroll
            for (int off = 32; off > 0; off >>= 1) {
                ls  += __shfl_xor(ls,  off, 64);
                neg ^= __shfl_xor(neg, off, 64);
            }
            unsigned long long vis0 = 0ull, vis1 = 0ull;
            int trans = 0;
            for (int k = 0; k < 128; ++k) {
                bool vk = (k < 64) ? ((vis0 >> k) & 1ull) : ((vis1 >> (k - 64)) & 1ull);
                if (!vk) {
                    int j = k, len = 0;
                    while (true) {
                        bool vj = (j < 64) ? ((vis0 >> j) & 1ull) : ((vis1 >> (j - 64)) & 1ull);
                        if (vj) break;
                        if (j < 64) vis0 |= (1ull << j); else vis1 |= (1ull << (j - 64));
                        j = (j < 64) ? __builtin_amdgcn_readlane(ps0, j)
                                     : __builtin_amdgcn_readlane(ps1, j - 64);
                        ++len;
                    }
                    trans += len - 1;
                }
            }
            if (lane == 0) {
                int parity = (neg ^ (trans & 1)) & 1;
                out[bA + s]      = ls;
                out[BB + bA + s] = parity ? (float)M_PI : 0.0f;
            }
        }
    }
}

// ---------------------------------------------------------------------------
extern "C" void kernel_launch(void* const* d_in, const int* in_sizes, int n_in,
                              void* d_out, int out_size, void* d_ws, size_t ws_size,
                              hipStream_t stream) {
    const int*   n       = (const int*)  d_in[0];
    const float* M_base  = (const float*)d_in[1];
    const float* lift_W  = (const float*)d_in[2];
    const float* lift_b  = (const float*)d_in[3];
    const float* spec_Wr = (const float*)d_in[4];
    const float* spec_Wi = (const float*)d_in[5];
    const float* pw_W    = (const float*)d_in[6];
    const float* pw_b    = (const float*)d_in[7];
    const float* proj_W  = (const float*)d_in[8];
    const float* proj_b  = (const float*)d_in[9];

    // ws layout: pooled 128KB | pos 512KB | (align 1MB) A_ws 64MB
    float*       pooled = (float*)d_ws;
    signed char* pos    = (signed char*)((char*)d_ws + 128*1024);
    float*       A_ws   = (float*)((char*)d_ws + (1 << 20));

    fno_pooled_kernel<<<BB, 256, 0, stream>>>(n, lift_W, lift_b, spec_Wr, spec_Wi,
                                              pw_W, pw_b, pooled, pos);
    build_kernel<<<SIZE*4, 128, 0, stream>>>(M_base, proj_W, proj_b, pooled, pos, A_ws);
    lu_kernel<<<BB/2, 512, 0, stream>>>(A_ws, (float*)d_out);
}

// Round 14
// 341.228 us; speedup vs baseline: 1.8897x; 1.2302x over previous
//
#include <hip/hip_runtime.h>
#include <math.h>

#ifndef M_PI
#define M_PI 3.14159265358979323846
#endif

#define BB 1024
#define SIZE 512
#define NF 128
#define WIDTH 32
#define TOTAL (SIZE*NF)

// DPP-based unsigned max reduce step (VALU latency, no LDS pipe)
#define DPP_UMAX(x, ctrl, rmask) { \
    unsigned _t = (unsigned)__builtin_amdgcn_update_dpp(0, (int)(x), (ctrl), (rmask), 0xf, false); \
    if (_t > (x)) (x) = _t; }

__device__ __forceinline__ float readlanef(float x, int l) {
    return __int_as_float(__builtin_amdgcn_readlane(__float_as_int(x), l));
}

// ---------------------------------------------------------------------------
// Kernel 1: per-sample FNO frontend -> pooled[b][32], pos[r][b] (gather map)
// ---------------------------------------------------------------------------
__global__ __launch_bounds__(256) void fno_pooled_kernel(
    const int*   __restrict__ n,
    const float* __restrict__ lift_W,
    const float* __restrict__ lift_b,
    const float* __restrict__ spec_Wr,
    const float* __restrict__ spec_Wi,
    const float* __restrict__ pw_W,
    const float* __restrict__ pw_b,
    float* __restrict__ pooled_g,
    signed char* __restrict__ pos_g)
{
    __shared__ float nf[SIZE];
    __shared__ float c32[32], s32[32];
    __shared__ float Gre[16], Gim[16];
    __shared__ float wsum[4][32];
    __shared__ float Arr[WIDTH][16], Aii[WIDTH][16];
    __shared__ float lowr[WIDTH][16], lowi[WIDTH][16];
    __shared__ float pwl[WIDTH], cb0[WIDTH];
    __shared__ float Brr[WIDTH], Bii[WIDTH];

    const int b = blockIdx.x;
    const int t = threadIdx.x;
    const int lane = t & 63;
    const int wave = t >> 6;

    if (t < 32) {
        float ang = (float)t * (2.0f * (float)M_PI / 32.0f);
        c32[t] = cosf(ang);
        s32[t] = sinf(ang);
    }
    for (int p = t; p < SIZE; p += 256) nf[p] = (float)n[b*SIZE + p];
    __syncthreads();

    if (wave == 0) {
        int base = 0;
        for (int c = 0; c < 8; ++c) {
            int p = c*64 + lane;
            bool occ = (nf[p] != 0.0f);
            unsigned long long mask = __ballot(occ);
            int prefix = __popcll(mask & ((1ull << lane) - 1ull));
            int pos = base + prefix;
            pos_g[(size_t)p*BB + b] = (occ && pos < NF) ? (signed char)pos : (signed char)-1;
            base += __popcll(mask);
        }
    }

    float gre[16], gim[16];
    #pragma unroll
    for (int m = 0; m < 16; ++m) { gre[m] = 0.f; gim[m] = 0.f; }
    for (int p = t; p < SIZE; p += 256) {
        float v = nf[p];
        int x = p >> 4, y = p & 15;
        #pragma unroll
        for (int kx = 0; kx < 4; ++kx) {
            #pragma unroll
            for (int ky = 0; ky < 4; ++ky) {
                int idx = (kx*x + 2*ky*y) & 31;
                gre[kx*4+ky] += v * c32[idx];
                gim[kx*4+ky] -= v * s32[idx];
            }
        }
    }
    #pragma unroll
    for (int m = 0; m < 16; ++m) {
        for (int off = 32; off > 0; off >>= 1) {
            gre[m] += __shfl_xor(gre[m], off, 64);
            gim[m] += __shfl_xor(gim[m], off, 64);
        }
    }
    if (lane == 0) {
        #pragma unroll
        for (int m = 0; m < 16; ++m) { wsum[wave][m] = gre[m]; wsum[wave][16+m] = gim[m]; }
    }
    __syncthreads();
    if (t < 32) {
        float s = wsum[0][t] + wsum[1][t] + wsum[2][t] + wsum[3][t];
        if (t < 16) Gre[t] = s; else Gim[t-16] = s;
    }

    for (int idx = t; idx < 512; idx += 256) {
        int o = idx >> 4, m = idx & 15;
        float ar = 0.f, ai = 0.f;
        for (int ii = 0; ii < WIDTH; ++ii) {
            float lw = lift_W[ii];
            ar += lw * spec_Wr[ii*512 + o*16 + m];
            ai += lw * spec_Wi[ii*512 + o*16 + m];
        }
        Arr[o][m] = ar; Aii[o][m] = ai;
    }
    if (t < 32) {
        float br = 0.f, bi = 0.f, pl = 0.f, cb = 0.f;
        for (int ii = 0; ii < WIDTH; ++ii) {
            float lb = lift_b[ii];
            br += lb * spec_Wr[ii*512 + t*16 + 0];
            bi += lb * spec_Wi[ii*512 + t*16 + 0];
            pl += lift_W[ii] * pw_W[ii*WIDTH + t];
            cb += lb * pw_W[ii*WIDTH + t];
        }
        Brr[t] = br; Bii[t] = bi;
        pwl[t] = pl;
        cb0[t] = cb + pw_b[t];
    }
    __syncthreads();

    for (int idx = t; idx < 512; idx += 256) {
        int o = idx >> 4, m = idx & 15;
        float gr = Gre[m], gi = Gim[m];
        float ar = Arr[o][m], ai = Aii[o][m];
        float lr = gr*ar - gi*ai;
        float li = gr*ai + gi*ar;
        if (m == 0) { lr += 512.f * Brr[o]; li += 512.f * Bii[o]; }
        lowr[o][m] = lr; lowi[o][m] = li;
    }
    __syncthreads();

    const int o  = t >> 3;
    const int xg = t & 7;
    const float plo = pwl[o], cbo = cb0[o];
    float acc = 0.f;
    const float inv32 = 1.0f/32.0f, inv16 = 1.0f/16.0f;
    for (int xi = 0; xi < 4; ++xi) {
        int x = xg*4 + xi;
        float Tre[4], Tim[4];
        #pragma unroll
        for (int ky = 0; ky < 4; ++ky) { Tre[ky] = 0.f; Tim[ky] = 0.f; }
        #pragma unroll
        for (int kx = 0; kx < 4; ++kx) {
            int idx = (kx*x) & 31;
            float c = c32[idx], s = s32[idx];
            #pragma unroll
            for (int ky = 0; ky < 4; ++ky) {
                float lr = lowr[o][kx*4+ky], li = lowi[o][kx*4+ky];
                Tre[ky] += lr*c - li*s;
                Tim[ky] += lr*s + li*c;
            }
        }
        #pragma unroll
        for (int ky = 0; ky < 4; ++ky) { Tre[ky] *= inv32; Tim[ky] *= inv32; }
        for (int y = 0; y < 16; ++y) {
            float hsv = Tre[0];
            #pragma unroll
            for (int ky = 1; ky < 4; ++ky) {
                int idx = (2*ky*y) & 31;
                hsv += 2.f*(Tre[ky]*c32[idx] - Tim[ky]*s32[idx]);
            }
            hsv *= inv16;
            float z = hsv + nf[x*16 + y]*plo + cbo;
            acc += tanhf(z);
        }
    }
    acc += __shfl_down(acc, 4, 8);
    acc += __shfl_down(acc, 2, 8);
    acc += __shfl_down(acc, 1, 8);
    if ((t & 7) == 0) pooled_g[b*WIDTH + o] = acc * (1.0f/512.0f);
}

// ---------------------------------------------------------------------------
// Kernel 2: r-major gathered build (proj_W row segment in registers, reused
// across 256 samples). Writes A_ws coalesced.
// ---------------------------------------------------------------------------
__global__ __launch_bounds__(128) void build_kernel(
    const float* __restrict__ M_base,
    const float* __restrict__ proj_W,
    const float* __restrict__ proj_b,
    const float* __restrict__ pooled_g,
    const signed char* __restrict__ pos_g,
    float* __restrict__ A_ws)
{
    __shared__ float pooled_l[256*WIDTH];   // 32 KB
    __shared__ signed char posl[256];

    const int r  = blockIdx.x >> 2;
    const int b0 = (blockIdx.x & 3) * 256;
    const int j  = threadIdx.x;

    {
        const float4* src = (const float4*)(pooled_g + (size_t)b0*WIDTH);
        float4* dst = (float4*)pooled_l;
        for (int idx = j; idx < 256*WIDTH/4; idx += 128) dst[idx] = src[idx];
        if (j < 64) ((int*)posl)[j] = ((const int*)(pos_g + (size_t)r*BB + b0))[j];
    }

    float wj[WIDTH];
    #pragma unroll
    for (int o = 0; o < WIDTH; ++o) wj[o] = proj_W[(size_t)o*TOTAL + r*NF + j];
    const float base = M_base[r*NF + j] + proj_b[r*NF + j];
    __syncthreads();

    for (int bb = 0; bb < 256; ++bb) {
        int pos = posl[bb];
        if (pos < 0) continue;
        const float* pl = &pooled_l[bb*WIDTH];
        float acc = base;
        #pragma unroll
        for (int o = 0; o < WIDTH; ++o) acc += pl[o]*wj[o];
        A_ws[((size_t)(b0+bb)*NF + pos)*NF + j] = acc;
    }
}

// ---------------------------------------------------------------------------
// Kernel 3: rank-8 LU, A in registers, ALL-WAVE REDUNDANT PIVOT.
// 512 threads, 8 waves: thread t -> wave w=t>>6, lane l=t&63; half = w&1,
// quarter q = w>>1; row i = l + 64*half; owns cols q*32..q*32+31 (8 float4).
// Every wave runs the identical DPP pivot chain on the shared panel columns
// (pr8 register-uniform, no wave idles); each thread back-substitutes coefs
// for ITS OWN row in registers (no LDS coef exchange). 2 barriers/panel.
// Static LDS padded to ~61 KB: forces 2 blocks/CU -> allocator grants ~128
// VGPR budget (R13 evidence) so Areg + pivot working set never spill.
// Output planar: out[b] = logabs, out[BB+b] = 0 or pi.
// ---------------------------------------------------------------------------
__global__ __launch_bounds__(512) void lu_kernel(
    const float* __restrict__ A_ws,
    float* __restrict__ out)
{
    __shared__ __align__(16) float pcolA[128*4];   // panel cols 0-3 (2 KB)
    __shared__ __align__(16) float pcolB[128*4];   // panel cols 4-7 (2 KB)
    __shared__ __align__(16) float Raw[8*128];     // pre-panel pivot rows (4 KB)
    __shared__ float pvbuf[128];
    __shared__ int   pivseq[128];
    __shared__ float pad[13056];                   // 51 KB occupancy pad (see below)

    const int t = threadIdx.x;
    const int l = t & 63;
    const int w = t >> 6;
    const int half = w & 1;
    const int q = w >> 1;
    const int i = l + 64*half;
    const int b = blockIdx.x;

    // Unprovable-at-compile-time use of pad (A_ws is a runtime pointer):
    // keeps the 51 KB static so the backend sees 2 blocks/CU -> 128-VGPR budget.
    if (A_ws == nullptr) { pad[t] = (float)t; out[0] = pad[t]; return; }

    float4 Areg[8];
    {
        const float4* src = (const float4*)(A_ws + (size_t)b*(NF*NF) + i*NF + q*32);
        #pragma unroll
        for (int g = 0; g < 8; ++g) Areg[g] = src[g];
        if (q == 0) {
            *((float4*)&pcolA[i*4]) = Areg[0];
            *((float4*)&pcolB[i*4]) = Areg[1];
        }
    }
    bool done_i = false;
    bool done0 = false, done1 = false;   // per-lane retire masks (identical in all waves)
    __syncthreads();

    for (int p = 0; p < 16; ++p) {
        // ---------- all waves: redundant pivot chain on panel p ----------
        float4 a0v = *((const float4*)&pcolA[l*4]);
        float4 b0v = *((const float4*)&pcolB[l*4]);
        float4 a1v = *((const float4*)&pcolA[l*4 + 256]);
        float4 b1v = *((const float4*)&pcolB[l*4 + 256]);
        float v0[8] = { a0v.x,a0v.y,a0v.z,a0v.w, b0v.x,b0v.y,b0v.z,b0v.w };
        float v1[8] = { a1v.x,a1v.y,a1v.z,a1v.w, b1v.x,b1v.y,b1v.z,b1v.w };
        float lr0[8], lr1[8];
        int   prreg[8];

        #pragma unroll
        for (int k = 0; k < 8; ++k) {
            unsigned aa0 = __float_as_uint(v0[k]) & 0x7fffffffu;
            unsigned aa1 = __float_as_uint(v1[k]) & 0x7fffffffu;
            unsigned key0 = done0 ? 0u : ((aa0 & 0xffffff80u) | (unsigned)l);
            unsigned key1 = done1 ? 0u : ((aa1 & 0xffffff80u) | (unsigned)(l + 64));
            unsigned key = (key1 > key0) ? key1 : key0;
            DPP_UMAX(key, 0x111, 0xf);   // row_shr:1
            DPP_UMAX(key, 0x112, 0xf);   // row_shr:2
            DPP_UMAX(key, 0x114, 0xf);   // row_shr:4
            DPP_UMAX(key, 0x118, 0xf);   // row_shr:8
            DPP_UMAX(key, 0x142, 0xa);   // row_bcast:15
            DPP_UMAX(key, 0x143, 0xc);   // row_bcast:31
            const unsigned best = (unsigned)__builtin_amdgcn_readlane((int)key, 63);
            const int row = (int)(best & 127u);
            const int lw  = row & 63;
            const bool lowh = (row < 64);
            const float pv = lowh ? readlanef(v0[k], lw) : readlanef(v1[k], lw);
            prreg[k] = row;
            const float inv = 1.0f / pv;
            float l0 = (done0 || row == l)      ? 0.f : v0[k] * inv;
            float l1 = (done1 || row == l + 64) ? 0.f : v1[k] * inv;
            lr0[k] = l0; lr1[k] = l1;
            if (row == l)      done0 = true;
            if (row == l + 64) done1 = true;
            #pragma unroll
            for (int j = 0; j < 8; ++j) if (j > k) {
                float ukj = lowh ? readlanef(v0[j], lw) : readlanef(v1[j], lw);
                v0[j] -= l0 * ukj;
                v1[j] -= l1 * ukj;
            }
            if (w == 0 && l == 0) { pivseq[8*p+k] = row; pvbuf[8*p+k] = pv; }
        }

        // ---------- per-thread coefs for OWN row (back-sub, Lt fused) ----------
        float cs[8];
        {
            float lm[8];
            #pragma unroll
            for (int s = 0; s < 8; ++s) lm[s] = half ? lr1[s] : lr0[s];
            #pragma unroll
            for (int s2 = 7; s2 >= 0; --s2) {
                float acc = -lm[s2];
                #pragma unroll
                for (int sp = 7; sp > 0; --sp) if (sp > s2) {
                    float Lt = (prreg[sp] < 64) ? readlanef(lr0[s2], prreg[sp])
                                                : readlanef(lr1[s2], prreg[sp] - 64);
                    acc -= cs[sp] * Lt;
                }
                cs[s2] = acc;
            }
        }

        // ---------- pivot-row owners publish Raw (pre-panel values) ----------
        int fp = -1;
        #pragma unroll
        for (int s = 0; s < 8; ++s) if (i == prreg[s]) fp = s;
        if (fp >= 0) {
            #pragma unroll
            for (int g = 0; g < 8; ++g)
                *((float4*)&Raw[fp*128 + (q*8 + g)*4]) = Areg[g];
        }
        __syncthreads();   // barrier 1: Raw ready

        // ---------- rank-8 update of own row + publish pcol(p+1) ----------
        if (fp >= 0) {
            done_i = true;   // retired; trailing values never read again
        } else if (!done_i) {
            #pragma unroll
            for (int g = 0; g < 8; ++g) {
                const int G = q*8 + g;
                if (G > 2*p + 1) {
                    const int cbase = G*4;
                    float4 own = Areg[g];
                    #pragma unroll
                    for (int s = 0; s < 8; ++s) {
                        const float4 rv = *((const float4*)&Raw[s*128 + cbase]);
                        own.x += cs[s]*rv.x; own.y += cs[s]*rv.y;
                        own.z += cs[s]*rv.z; own.w += cs[s]*rv.w;
                    }
                    Areg[g] = own;
                    if (G == 2*p + 2) *((float4*)&pcolA[i*4]) = own;
                    if (G == 2*p + 3) *((float4*)&pcolB[i*4]) = own;
                }
            }
        }
        __syncthreads();   // barrier 2: Areg stable + pcol(p+1) ready
    }

    // ---------- logabs + sign (wave 0) ----------
    if (w == 0) {
        float d0 = pvbuf[l], d1 = pvbuf[l + 64];
        int   ps0 = pivseq[l], ps1 = pivseq[l + 64];
        float ls = logf(fabsf(d0)) + logf(fabsf(d1));
        int neg = ((d0 < 0.f) ? 1 : 0) ^ ((d1 < 0.f) ? 1 : 0);
        #pragma unroll
        for (int off = 32; off > 0; off >>= 1) {
            ls  += __shfl_xor(ls,  off, 64);
            neg ^= __shfl_xor(neg, off, 64);
        }
        unsigned long long vis0 = 0ull, vis1 = 0ull;
        int trans = 0;
        for (int k = 0; k < 128; ++k) {
            bool vk = (k < 64) ? ((vis0 >> k) & 1ull) : ((vis1 >> (k - 64)) & 1ull);
            if (!vk) {
                int j = k, len = 0;
                while (true) {
                    bool vj = (j < 64) ? ((vis0 >> j) & 1ull) : ((vis1 >> (j - 64)) & 1ull);
                    if (vj) break;
                    if (j < 64) vis0 |= (1ull << j); else vis1 |= (1ull << (j - 64));
                    j = (j < 64) ? __builtin_amdgcn_readlane(ps0, j)
                                 : __builtin_amdgcn_readlane(ps1, j - 64);
                    ++len;
                }
                trans += len - 1;
            }
        }
        if (l == 0) {
            int parity = (neg ^ (trans & 1)) & 1;
            out[b]      = ls;
            out[BB + b] = parity ? (float)M_PI : 0.0f;
        }
    }
}

// ---------------------------------------------------------------------------
extern "C" void kernel_launch(void* const* d_in, const int* in_sizes, int n_in,
                              void* d_out, int out_size, void* d_ws, size_t ws_size,
                              hipStream_t stream) {
    const int*   n       = (const int*)  d_in[0];
    const float* M_base  = (const float*)d_in[1];
    const float* lift_W  = (const float*)d_in[2];
    const float* lift_b  = (const float*)d_in[3];
    const float* spec_Wr = (const float*)d_in[4];
    const float* spec_Wi = (const float*)d_in[5];
    const float* pw_W    = (const float*)d_in[6];
    const float* pw_b    = (const float*)d_in[7];
    const float* proj_W  = (const float*)d_in[8];
    const float* proj_b  = (const float*)d_in[9];

    // ws layout: pooled 128KB | pos 512KB | (align 1MB) A_ws 64MB
    float*       pooled = (float*)d_ws;
    signed char* pos    = (signed char*)((char*)d_ws + 128*1024);
    float*       A_ws   = (float*)((char*)d_ws + (1 << 20));

    fno_pooled_kernel<<<BB, 256, 0, stream>>>(n, lift_W, lift_b, spec_Wr, spec_Wi,
                                              pw_W, pw_b, pooled, pos);
    build_kernel<<<SIZE*4, 128, 0, stream>>>(M_base, proj_W, proj_b, pooled, pos, A_ws);
    lu_kernel<<<BB, 512, 0, stream>>>(A_ws, (float*)d_out);
}

// Round 15
// 303.161 us; speedup vs baseline: 2.1270x; 1.1256x over previous
//
#include <hip/hip_runtime.h>
#include <math.h>

#ifndef M_PI
#define M_PI 3.14159265358979323846
#endif

#define BB 1024
#define SIZE 512
#define NF 128
#define WIDTH 32
#define TOTAL (SIZE*NF)

// DPP-based unsigned max reduce step (VALU latency, no LDS pipe)
#define DPP_UMAX(x, ctrl, rmask) { \
    unsigned _t = (unsigned)__builtin_amdgcn_update_dpp(0, (int)(x), (ctrl), (rmask), 0xf, false); \
    if (_t > (x)) (x) = _t; }

__device__ __forceinline__ float readlanef(float x, int l) {
    return __int_as_float(__builtin_amdgcn_readlane(__float_as_int(x), l));
}

// fast reciprocal: v_rcp_f32 + 1 Newton step (~1 ulp)
__device__ __forceinline__ float frcp_fast(float x) {
    float r = __builtin_amdgcn_rcpf(x);
    return r * (2.0f - x * r);
}

// ---------------------------------------------------------------------------
// Kernel 1: per-sample FNO frontend -> pooled[b][32], pos[r][b] (gather map)
// ---------------------------------------------------------------------------
__global__ __launch_bounds__(256) void fno_pooled_kernel(
    const int*   __restrict__ n,
    const float* __restrict__ lift_W,
    const float* __restrict__ lift_b,
    const float* __restrict__ spec_Wr,
    const float* __restrict__ spec_Wi,
    const float* __restrict__ pw_W,
    const float* __restrict__ pw_b,
    float* __restrict__ pooled_g,
    signed char* __restrict__ pos_g)
{
    __shared__ float nf[SIZE];
    __shared__ float c32[32], s32[32];
    __shared__ float Gre[16], Gim[16];
    __shared__ float wsum[4][32];
    __shared__ float Arr[WIDTH][16], Aii[WIDTH][16];
    __shared__ float lowr[WIDTH][16], lowi[WIDTH][16];
    __shared__ float pwl[WIDTH], cb0[WIDTH];
    __shared__ float Brr[WIDTH], Bii[WIDTH];

    const int b = blockIdx.x;
    const int t = threadIdx.x;
    const int lane = t & 63;
    const int wave = t >> 6;

    if (t < 32) {
        float ang = (float)t * (2.0f * (float)M_PI / 32.0f);
        c32[t] = cosf(ang);
        s32[t] = sinf(ang);
    }
    for (int p = t; p < SIZE; p += 256) nf[p] = (float)n[b*SIZE + p];
    __syncthreads();

    if (wave == 0) {
        int base = 0;
        for (int c = 0; c < 8; ++c) {
            int p = c*64 + lane;
            bool occ = (nf[p] != 0.0f);
            unsigned long long mask = __ballot(occ);
            int prefix = __popcll(mask & ((1ull << lane) - 1ull));
            int pos = base + prefix;
            pos_g[(size_t)p*BB + b] = (occ && pos < NF) ? (signed char)pos : (signed char)-1;
            base += __popcll(mask);
        }
    }

    float gre[16], gim[16];
    #pragma unroll
    for (int m = 0; m < 16; ++m) { gre[m] = 0.f; gim[m] = 0.f; }
    for (int p = t; p < SIZE; p += 256) {
        float v = nf[p];
        int x = p >> 4, y = p & 15;
        #pragma unroll
        for (int kx = 0; kx < 4; ++kx) {
            #pragma unroll
            for (int ky = 0; ky < 4; ++ky) {
                int idx = (kx*x + 2*ky*y) & 31;
                gre[kx*4+ky] += v * c32[idx];
                gim[kx*4+ky] -= v * s32[idx];
            }
        }
    }
    #pragma unroll
    for (int m = 0; m < 16; ++m) {
        for (int off = 32; off > 0; off >>= 1) {
            gre[m] += __shfl_xor(gre[m], off, 64);
            gim[m] += __shfl_xor(gim[m], off, 64);
        }
    }
    if (lane == 0) {
        #pragma unroll
        for (int m = 0; m < 16; ++m) { wsum[wave][m] = gre[m]; wsum[wave][16+m] = gim[m]; }
    }
    __syncthreads();
    if (t < 32) {
        float s = wsum[0][t] + wsum[1][t] + wsum[2][t] + wsum[3][t];
        if (t < 16) Gre[t] = s; else Gim[t-16] = s;
    }

    for (int idx = t; idx < 512; idx += 256) {
        int o = idx >> 4, m = idx & 15;
        float ar = 0.f, ai = 0.f;
        for (int ii = 0; ii < WIDTH; ++ii) {
            float lw = lift_W[ii];
            ar += lw * spec_Wr[ii*512 + o*16 + m];
            ai += lw * spec_Wi[ii*512 + o*16 + m];
        }
        Arr[o][m] = ar; Aii[o][m] = ai;
    }
    if (t < 32) {
        float br = 0.f, bi = 0.f, pl = 0.f, cb = 0.f;
        for (int ii = 0; ii < WIDTH; ++ii) {
            float lb = lift_b[ii];
            br += lb * spec_Wr[ii*512 + t*16 + 0];
            bi += lb * spec_Wi[ii*512 + t*16 + 0];
            pl += lift_W[ii] * pw_W[ii*WIDTH + t];
            cb += lb * pw_W[ii*WIDTH + t];
        }
        Brr[t] = br; Bii[t] = bi;
        pwl[t] = pl;
        cb0[t] = cb + pw_b[t];
    }
    __syncthreads();

    for (int idx = t; idx < 512; idx += 256) {
        int o = idx >> 4, m = idx & 15;
        float gr = Gre[m], gi = Gim[m];
        float ar = Arr[o][m], ai = Aii[o][m];
        float lr = gr*ar - gi*ai;
        float li = gr*ai + gi*ar;
        if (m == 0) { lr += 512.f * Brr[o]; li += 512.f * Bii[o]; }
        lowr[o][m] = lr; lowi[o][m] = li;
    }
    __syncthreads();

    const int o  = t >> 3;
    const int xg = t & 7;
    const float plo = pwl[o], cbo = cb0[o];
    float acc = 0.f;
    const float inv32 = 1.0f/32.0f, inv16 = 1.0f/16.0f;
    for (int xi = 0; xi < 4; ++xi) {
        int x = xg*4 + xi;
        float Tre[4], Tim[4];
        #pragma unroll
        for (int ky = 0; ky < 4; ++ky) { Tre[ky] = 0.f; Tim[ky] = 0.f; }
        #pragma unroll
        for (int kx = 0; kx < 4; ++kx) {
            int idx = (kx*x) & 31;
            float c = c32[idx], s = s32[idx];
            #pragma unroll
            for (int ky = 0; ky < 4; ++ky) {
                float lr = lowr[o][kx*4+ky], li = lowi[o][kx*4+ky];
                Tre[ky] += lr*c - li*s;
                Tim[ky] += lr*s + li*c;
            }
        }
        #pragma unroll
        for (int ky = 0; ky < 4; ++ky) { Tre[ky] *= inv32; Tim[ky] *= inv32; }
        for (int y = 0; y < 16; ++y) {
            float hsv = Tre[0];
            #pragma unroll
            for (int ky = 1; ky < 4; ++ky) {
                int idx = (2*ky*y) & 31;
                hsv += 2.f*(Tre[ky]*c32[idx] - Tim[ky]*s32[idx]);
            }
            hsv *= inv16;
            float z = hsv + nf[x*16 + y]*plo + cbo;
            acc += tanhf(z);
        }
    }
    acc += __shfl_down(acc, 4, 8);
    acc += __shfl_down(acc, 2, 8);
    acc += __shfl_down(acc, 1, 8);
    if ((t & 7) == 0) pooled_g[b*WIDTH + o] = acc * (1.0f/512.0f);
}

// ---------------------------------------------------------------------------
// Kernel 2: r-major gathered build. 256 threads: j = t&127, sub = t>>7.
// proj_W row segment in registers, reused over 128 samples per sub-half.
// Per-sample pooled vector hoisted via 8 x ds_read_b128 broadcast.
// ---------------------------------------------------------------------------
__global__ __launch_bounds__(256) void build_kernel(
    const float* __restrict__ M_base,
    const float* __restrict__ proj_W,
    const float* __restrict__ proj_b,
    const float* __restrict__ pooled_g,
    const signed char* __restrict__ pos_g,
    float* __restrict__ A_ws)
{
    __shared__ float pooled_l[256*WIDTH];   // 32 KB
    __shared__ signed char posl[256];

    const int r   = blockIdx.x >> 2;
    const int b0  = (blockIdx.x & 3) * 256;
    const int t   = threadIdx.x;
    const int j   = t & 127;
    const int sub = t >> 7;

    {
        const float4* src = (const float4*)(pooled_g + (size_t)b0*WIDTH);
        float4* dst = (float4*)pooled_l;
        for (int idx = t; idx < 256*WIDTH/4; idx += 256) dst[idx] = src[idx];
        if (t < 64) ((int*)posl)[t] = ((const int*)(pos_g + (size_t)r*BB + b0))[t];
    }

    float wj[WIDTH];
    #pragma unroll
    for (int o = 0; o < WIDTH; ++o) wj[o] = proj_W[(size_t)o*TOTAL + r*NF + j];
    const float base = M_base[r*NF + j] + proj_b[r*NF + j];
    __syncthreads();

    for (int bb = sub; bb < 256; bb += 2) {
        int pos = posl[bb];
        if (pos < 0) continue;
        const float4* pl4 = (const float4*)&pooled_l[bb*WIDTH];
        float4 p0 = pl4[0], p1 = pl4[1], p2 = pl4[2], p3 = pl4[3];
        float4 p4 = pl4[4], p5 = pl4[5], p6 = pl4[6], p7 = pl4[7];
        float acc = base;
        acc += p0.x*wj[0]  + p0.y*wj[1]  + p0.z*wj[2]  + p0.w*wj[3];
        acc += p1.x*wj[4]  + p1.y*wj[5]  + p1.z*wj[6]  + p1.w*wj[7];
        acc += p2.x*wj[8]  + p2.y*wj[9]  + p2.z*wj[10] + p2.w*wj[11];
        acc += p3.x*wj[12] + p3.y*wj[13] + p3.z*wj[14] + p3.w*wj[15];
        acc += p4.x*wj[16] + p4.y*wj[17] + p4.z*wj[18] + p4.w*wj[19];
        acc += p5.x*wj[20] + p5.y*wj[21] + p5.z*wj[22] + p5.w*wj[23];
        acc += p6.x*wj[24] + p6.y*wj[25] + p6.z*wj[26] + p6.w*wj[27];
        acc += p7.x*wj[28] + p7.y*wj[29] + p7.z*wj[30] + p7.w*wj[31];
        A_ws[((size_t)(b0+bb)*NF + pos)*NF + j] = acc;
    }
}

// ---------------------------------------------------------------------------
// Kernel 3: rank-8 LU, A in registers, ALL-WAVE REDUNDANT PIVOT (R14 proven).
// 512 threads, 8 waves: w=t>>6, l=t&63; half=w&1, q=w>>1; row i=l+64*half;
// owns cols q*32..q*32+31 (8 float4). Every wave runs the identical DPP
// pivot chain (no wave idles); per-thread coef back-sub for own row.
// 2 barriers/panel. Fast rcp (+1 NR) replaces IEEE divide on the chain.
// Output planar: out[b] = logabs, out[BB+b] = 0 or pi.
// ---------------------------------------------------------------------------
__global__ __launch_bounds__(512) void lu_kernel(
    const float* __restrict__ A_ws,
    float* __restrict__ out)
{
    __shared__ __align__(16) float pcolA[128*4];   // panel cols 0-3 (2 KB)
    __shared__ __align__(16) float pcolB[128*4];   // panel cols 4-7 (2 KB)
    __shared__ __align__(16) float Raw[8*128];     // pre-panel pivot rows (4 KB)
    __shared__ float pvbuf[128];
    __shared__ int   pivseq[128];

    const int t = threadIdx.x;
    const int l = t & 63;
    const int w = t >> 6;
    const int half = w & 1;
    const int q = w >> 1;
    const int i = l + 64*half;
    const int b = blockIdx.x;

    float4 Areg[8];
    {
        const float4* src = (const float4*)(A_ws + (size_t)b*(NF*NF) + i*NF + q*32);
        #pragma unroll
        for (int g = 0; g < 8; ++g) Areg[g] = src[g];
        if (q == 0) {
            *((float4*)&pcolA[i*4]) = Areg[0];
            *((float4*)&pcolB[i*4]) = Areg[1];
        }
    }
    bool done_i = false;
    bool done0 = false, done1 = false;   // per-lane retire masks (identical in all waves)
    __syncthreads();

    for (int p = 0; p < 16; ++p) {
        // ---------- all waves: redundant pivot chain on panel p ----------
        float4 a0v = *((const float4*)&pcolA[l*4]);
        float4 b0v = *((const float4*)&pcolB[l*4]);
        float4 a1v = *((const float4*)&pcolA[l*4 + 256]);
        float4 b1v = *((const float4*)&pcolB[l*4 + 256]);
        float v0[8] = { a0v.x,a0v.y,a0v.z,a0v.w, b0v.x,b0v.y,b0v.z,b0v.w };
        float v1[8] = { a1v.x,a1v.y,a1v.z,a1v.w, b1v.x,b1v.y,b1v.z,b1v.w };
        float lr0[8], lr1[8];
        int   prreg[8];

        #pragma unroll
        for (int k = 0; k < 8; ++k) {
            unsigned aa0 = __float_as_uint(v0[k]) & 0x7fffffffu;
            unsigned aa1 = __float_as_uint(v1[k]) & 0x7fffffffu;
            unsigned key0 = done0 ? 0u : ((aa0 & 0xffffff80u) | (unsigned)l);
            unsigned key1 = done1 ? 0u : ((aa1 & 0xffffff80u) | (unsigned)(l + 64));
            unsigned key = (key1 > key0) ? key1 : key0;
            DPP_UMAX(key, 0x111, 0xf);   // row_shr:1
            DPP_UMAX(key, 0x112, 0xf);   // row_shr:2
            DPP_UMAX(key, 0x114, 0xf);   // row_shr:4
            DPP_UMAX(key, 0x118, 0xf);   // row_shr:8
            DPP_UMAX(key, 0x142, 0xa);   // row_bcast:15
            DPP_UMAX(key, 0x143, 0xc);   // row_bcast:31
            const unsigned best = (unsigned)__builtin_amdgcn_readlane((int)key, 63);
            const int row = (int)(best & 127u);
            const int lw  = row & 63;
            const bool lowh = (row < 64);
            const float pv = lowh ? readlanef(v0[k], lw) : readlanef(v1[k], lw);
            prreg[k] = row;
            const float inv = frcp_fast(pv);
            float l0 = (done0 || row == l)      ? 0.f : v0[k] * inv;
            float l1 = (done1 || row == l + 64) ? 0.f : v1[k] * inv;
            lr0[k] = l0; lr1[k] = l1;
            if (row == l)      done0 = true;
            if (row == l + 64) done1 = true;
            #pragma unroll
            for (int j = 0; j < 8; ++j) if (j > k) {
                float ukj = lowh ? readlanef(v0[j], lw) : readlanef(v1[j], lw);
                v0[j] -= l0 * ukj;
                v1[j] -= l1 * ukj;
            }
            if (w == 0 && l == 0) { pivseq[8*p+k] = row; pvbuf[8*p+k] = pv; }
        }

        // ---------- per-thread coefs for OWN row (back-sub, Lt fused) ----------
        float cs[8];
        {
            float lm[8];
            #pragma unroll
            for (int s = 0; s < 8; ++s) lm[s] = half ? lr1[s] : lr0[s];
            #pragma unroll
            for (int s2 = 7; s2 >= 0; --s2) {
                float acc = -lm[s2];
                #pragma unroll
                for (int sp = 7; sp > 0; --sp) if (sp > s2) {
                    float Lt = (prreg[sp] < 64) ? readlanef(lr0[s2], prreg[sp])
                                                : readlanef(lr1[s2], prreg[sp] - 64);
                    acc -= cs[sp] * Lt;
                }
                cs[s2] = acc;
            }
        }

        // ---------- pivot-row owners publish Raw (pre-panel values) ----------
        int fp = -1;
        #pragma unroll
        for (int s = 0; s < 8; ++s) if (i == prreg[s]) fp = s;
        if (fp >= 0) {
            #pragma unroll
            for (int g = 0; g < 8; ++g)
                *((float4*)&Raw[fp*128 + (q*8 + g)*4]) = Areg[g];
        }
        __syncthreads();   // barrier 1: Raw ready

        // ---------- rank-8 update of own row + publish pcol(p+1) ----------
        if (fp >= 0) {
            done_i = true;   // retired; trailing values never read again
        } else if (!done_i) {
            #pragma unroll
            for (int g = 0; g < 8; ++g) {
                const int G = q*8 + g;
                if (G > 2*p + 1) {
                    const int cbase = G*4;
                    float4 own = Areg[g];
                    #pragma unroll
                    for (int s = 0; s < 8; ++s) {
                        const float4 rv = *((const float4*)&Raw[s*128 + cbase]);
                        own.x += cs[s]*rv.x; own.y += cs[s]*rv.y;
                        own.z += cs[s]*rv.z; own.w += cs[s]*rv.w;
                    }
                    Areg[g] = own;
                    if (G == 2*p + 2) *((float4*)&pcolA[i*4]) = own;
                    if (G == 2*p + 3) *((float4*)&pcolB[i*4]) = own;
                }
            }
        }
        __syncthreads();   // barrier 2: Areg stable + pcol(p+1) ready
    }

    // ---------- logabs + sign (wave 0) ----------
    if (w == 0) {
        float d0 = pvbuf[l], d1 = pvbuf[l + 64];
        int   ps0 = pivseq[l], ps1 = pivseq[l + 64];
        float ls = logf(fabsf(d0)) + logf(fabsf(d1));
        int neg = ((d0 < 0.f) ? 1 : 0) ^ ((d1 < 0.f) ? 1 : 0);
        #pragma unroll
        for (int off = 32; off > 0; off >>= 1) {
            ls  += __shfl_xor(ls,  off, 64);
            neg ^= __shfl_xor(neg, off, 64);
        }
        unsigned long long vis0 = 0ull, vis1 = 0ull;
        int trans = 0;
        for (int k = 0; k < 128; ++k) {
            bool vk = (k < 64) ? ((vis0 >> k) & 1ull) : ((vis1 >> (k - 64)) & 1ull);
            if (!vk) {
                int j = k, len = 0;
                while (true) {
                    bool vj = (j < 64) ? ((vis0 >> j) & 1ull) : ((vis1 >> (j - 64)) & 1ull);
                    if (vj) break;
                    if (j < 64) vis0 |= (1ull << j); else vis1 |= (1ull << (j - 64));
                    j = (j < 64) ? __builtin_amdgcn_readlane(ps0, j)
                                 : __builtin_amdgcn_readlane(ps1, j - 64);
                    ++len;
                }
                trans += len - 1;
            }
        }
        if (l == 0) {
            int parity = (neg ^ (trans & 1)) & 1;
            out[b]      = ls;
            out[BB + b] = parity ? (float)M_PI : 0.0f;
        }
    }
}

// ---------------------------------------------------------------------------
extern "C" void kernel_launch(void* const* d_in, const int* in_sizes, int n_in,
                              void* d_out, int out_size, void* d_ws, size_t ws_size,
                              hipStream_t stream) {
    const int*   n       = (const int*)  d_in[0];
    const float* M_base  = (const float*)d_in[1];
    const float* lift_W  = (const float*)d_in[2];
    const float* lift_b  = (const float*)d_in[3];
    const float* spec_Wr = (const float*)d_in[4];
    const float* spec_Wi = (const float*)d_in[5];
    const float* pw_W    = (const float*)d_in[6];
    const float* pw_b    = (const float*)d_in[7];
    const float* proj_W  = (const float*)d_in[8];
    const float* proj_b  = (const float*)d_in[9];

    // ws layout: pooled 128KB | pos 512KB | (align 1MB) A_ws 64MB
    float*       pooled = (float*)d_ws;
    signed char* pos    = (signed char*)((char*)d_ws + 128*1024);
    float*       A_ws   = (float*)((char*)d_ws + (1 << 20));

    fno_pooled_kernel<<<BB, 256, 0, stream>>>(n, lift_W, lift_b, spec_Wr, spec_Wi,
                                              pw_W, pw_b, pooled, pos);
    build_kernel<<<SIZE*4, 256, 0, stream>>>(M_base, proj_W, proj_b, pooled, pos, A_ws);
    lu_kernel<<<BB, 512, 0, stream>>>(A_ws, (float*)d_out);
}